// Round 9
// baseline (338.460 us; speedup 1.0000x reference)
//
#include <hip/hip_runtime.h>

// GCN 2-layer + pool + head, R24: R21 structure + open-line model fix + fused hist.
// Post-mortem R19-R23: partition write amplification ~ (blocks/XCD) x (K buckets x 64B
// write frontier). R21 (PB=256): 3.2MB/XCD open lines ~ L2 size -> 5x amp, 55us. R22/23
// detours (two-level radix, filter-gather) both regressed. Fix here:
//   k_part : PB=64 blocks x 1024 thr -> 0.8MB/XCD frontier (L2-resident, ~1x write amp).
//            Histograms its tile in LDS (feeds global bcnt atomically - k_cnt DELETED),
//            local scan -> private block-major region scatter (uint2 row|wq15, col).
//   k_scan : fine exclusive scan -> bstE (sentinel [K]=E).
//   k_grp  : per fine bucket, 64-run table (wave-0 shfl scan + u8 seg stamp), gather ->
//            group-by-col -> srt/cptr/dinv/g1b/acc1 (R21 form, 64 runs instead of 256).
//   k_csr  : 4 lanes/col, uint2 g-loads (half the waves of the 8-lane version).
//   k_mid, k_pool, k_final unchanged.
//   h[c] = b + dinv[c]*( g[c] + sum_e w_e * g[row_e] ),  g = dinv * (prev @ W)

#define SH 6
#define RB 64
#define KMAX 2048           // N <= 131072 (row packs in 17 bits)
#define KST (KMAX + 1)      // bof row stride
#define TPB 256
#define TPB_G 256           // k_grp threads
#define BCAP 8192           // per-bucket LDS capacity in k_grp
#define PT 1024             // k_part threads
#define PB 64               // partition grid (open-frontier model: 8 blocks/XCD)

typedef unsigned short ushort_t;
typedef unsigned char u8;
typedef unsigned long long u64;

__device__ __forceinline__ ushort_t f2bf(float v) {
    unsigned u = __float_as_uint(v);
    u += 0x7FFFu + ((u >> 16) & 1u);   // RNE
    return (ushort_t)(u >> 16);
}

__device__ __forceinline__ unsigned quantw(float w) {
    unsigned wq = (unsigned)__float2int_rn(w * 32768.0f);
    return wq > 32767u ? 32767u : wq;
}

// ---------- partition: fused hist(->bcnt) + local scan + block-major scatter ----------
__global__ __launch_bounds__(PT)
void k_part(const int* __restrict__ row, const int* __restrict__ col,
            const float* __restrict__ ew, unsigned* __restrict__ bcnt,
            unsigned* __restrict__ bof, uint2* __restrict__ brc,
            int E, int K, int tile) {
    __shared__ unsigned lh[KMAX];                // hist (8KB)
    __shared__ unsigned cur[KMAX];               // scatter cursors (8KB)
    __shared__ unsigned wt[PT / 64];
    int tid = threadIdx.x, b = blockIdx.x;
    int e0 = min(b * tile, E), e1 = min(b * tile + tile, E);
    unsigned base = (unsigned)e0;
    for (int i = tid; i < KMAX; i += PT) lh[i] = 0u;
    __syncthreads();
    for (int e = e0 + tid; e < e1; e += PT) atomicAdd(&lh[col[e] >> SH], 1u);
    __syncthreads();
    for (int i = tid; i < K; i += PT) {
        unsigned c = lh[i];
        if (c) atomicAdd(&bcnt[i], c);
    }
    // exclusive scan of lh (2 serial/thread + wave shfl + wave totals)
    int i0 = tid << 1;
    unsigned a0 = lh[i0], a1 = lh[i0 + 1];
    unsigned ts = a0 + a1, v = ts;
#pragma unroll
    for (int o = 1; o < 64; o <<= 1) {
        unsigned u = __shfl_up(v, o, 64);
        if ((tid & 63) >= o) v += u;
    }
    if ((tid & 63) == 63) wt[tid >> 6] = v;
    __syncthreads();
    if (tid == 0) {
        unsigned acc = 0;
#pragma unroll
        for (int w = 0; w < PT / 64; w++) { unsigned t = wt[w]; wt[w] = acc; acc += t; }
    }
    __syncthreads();
    unsigned ex = wt[tid >> 6] + (v - ts);
    unsigned* bo = bof + (size_t)b * KST;
    cur[i0] = base + ex;          bo[i0] = base + ex;
    cur[i0 + 1] = base + ex + a0; bo[i0 + 1] = base + ex + a0;
    if (tid == PT - 1) bo[KMAX] = base + ex + ts;
    __syncthreads();
    // scatter into private region; frontier = K lines/block, L2-resident at PB=64
    for (int e = e0 + tid; e < e1; e += PT) {
        int c = col[e];
        unsigned pos = atomicAdd(&cur[c >> SH], 1u);
        brc[pos] = make_uint2((unsigned)row[e] | (quantw(ew[e]) << 17), (unsigned)c);
    }
}

// ---------- exclusive scan over fine counts -> bstE[0..K] (sentinel [K]=E) ----------
__global__ void k_scan(const unsigned* __restrict__ cnt, unsigned* __restrict__ start,
                       int K) {
    __shared__ unsigned a[KMAX], b[KMAX];
    int t = threadIdx.x;  // 1024
    for (int i = t; i < KMAX; i += 1024) a[i] = (i < K) ? cnt[i] : 0u;
    __syncthreads();
    unsigned *src = a, *dst = b;
    for (int off = 1; off < KMAX; off <<= 1) {
        for (int i = t; i < KMAX; i += 1024)
            dst[i] = (i >= off) ? src[i] + src[i - off] : src[i];
        __syncthreads();
        unsigned* tmp = src; src = dst; dst = tmp;
    }
    for (int i = t; i <= K; i += 1024) start[i] = (i == 0) ? 0u : src[i - 1];
}

// ---------- per-bucket: gather 64 runs -> group-by-col -> srt + cptr + dinv + g1/acc1 ----
__global__ __launch_bounds__(TPB_G)
void k_grp(const uint2* __restrict__ brc, const unsigned* __restrict__ bof,
           const unsigned* __restrict__ bstE, const float* __restrict__ x,
           const float* __restrict__ W1, unsigned* __restrict__ srt,
           unsigned* __restrict__ cptr, float* __restrict__ dinv,
           unsigned* __restrict__ g1b, float* __restrict__ acc1,
           int N, int E, int K) {
    // bijective XCD-contiguous swizzle (m204): neighbor buckets read adjacent run bytes
    int orig = blockIdx.x;
    int q8 = K >> 3, r8 = K & 7;
    int xcd = orig & 7, idx = orig >> 3;
    int k = (xcd < r8 ? xcd * (q8 + 1) : r8 * (q8 + 1) + (xcd - r8) * q8) + idx;
    int node0 = k << SH;

    __shared__ unsigned ebuf[BCAP];          // 32KB (reused as gtmp after scatter)
    __shared__ u8 cbuf[BCAP];                // 8KB
    __shared__ u8 seg[BCAP];                 // 8KB: j -> run id
    __shared__ unsigned rsrc[PB];            // run source starts
    __shared__ unsigned roff[PB + 1];        // exclusive prefix of run lengths
    __shared__ unsigned cnt64[RB], st64[RB], dq[RB];
    __shared__ float dl[RB], lx[RB * 3], lw[48];
    int tid = threadIdx.x;
    unsigned s = bstE[k], c = bstE[k + 1] - s;
    if (tid < RB) { cnt64[tid] = 0u; dq[tid] = 0u; }
    if (tid < 48) lw[tid] = W1[tid];
    int nn = min(RB, N - node0);
    for (int i = tid; i < nn * 3; i += TPB_G) lx[i] = x[(size_t)node0 * 3 + i];

    // run table: 64 entries, scanned by wave 0
    if (tid < PB) {
        unsigned s0 = bof[(size_t)tid * KST + k];
        unsigned s1 = bof[(size_t)tid * KST + k + 1];
        rsrc[tid] = s0;
        unsigned rl = s1 - s0;
        unsigned v = rl;
#pragma unroll
        for (int o = 1; o < 64; o <<= 1) {
            unsigned u = __shfl_up(v, o, 64);
            if (tid >= o) v += u;
        }
        roff[tid] = v - rl;
        if (tid == PB - 1) roff[PB] = v;
    }
    __syncthreads();

    bool fits = (c <= (unsigned)BCAP);
    if (fits) {
        if (tid < PB) {                              // stamp run ids (avg 32B/thread)
            unsigned st = roff[tid], en = roff[tid + 1];
            for (unsigned j = st; j < en; ++j) seg[j] = (u8)tid;
        }
        __syncthreads();
        for (unsigned j = tid; j < c; j += TPB_G) {
            unsigned r = seg[j];
            unsigned src = rsrc[r] + (j - roff[r]);
            uint2 p = brc[src];
            unsigned cl = p.y & 63u;
            ebuf[j] = p.x; cbuf[j] = (u8)cl;
            atomicAdd(&cnt64[cl], 1u);
            atomicAdd(&dq[cl], p.x >> 17);
        }
    } else {                                         // fallback (rare): 6-step bsearch
#define MAP_SRC(j, srcv)                                                       \
        {                                                                      \
            int lo = 0, hi = PB - 1;                                           \
            _Pragma("unroll")                                                  \
            for (int it = 0; it < 6; ++it) {                                   \
                int mid = (lo + hi + 1) >> 1;                                  \
                if (roff[mid] <= (j)) lo = mid; else hi = mid - 1;             \
            }                                                                  \
            (srcv) = rsrc[lo] + ((j) - roff[lo]);                              \
        }
        for (unsigned j = tid; j < c; j += TPB_G) {
            unsigned src; MAP_SRC(j, src);
            uint2 p = brc[src];
            unsigned cl = p.y & 63u;
            atomicAdd(&cnt64[cl], 1u);
            atomicAdd(&dq[cl], p.x >> 17);
        }
    }
    __syncthreads();
    if (tid == 0) {                                  // tiny serial scan of 64
        unsigned acc = 0;
        for (int i = 0; i < RB; i++) { st64[i] = acc; acc += cnt64[i]; cnt64[i] = 0u; }
    }
    __syncthreads();
    if (fits) {
        for (unsigned j = tid; j < c; j += TPB_G) {
            unsigned cl = cbuf[j];
            unsigned pos = st64[cl] + atomicAdd(&cnt64[cl], 1u);
            srt[s + pos] = ebuf[j];                  // within-bucket contiguous range
        }
    } else {
        for (unsigned j = tid; j < c; j += TPB_G) {
            unsigned src; MAP_SRC(j, src);
            uint2 p = brc[src];
            unsigned cl = p.y & 63u;
            unsigned pos = st64[cl] + atomicAdd(&cnt64[cl], 1u);
            srt[s + pos] = p.x;
        }
#undef MAP_SRC
    }
    __syncthreads();
    if (tid < RB) {
        float d = rsqrtf(1.0f + (float)dq[tid] * (1.0f / 32768.0f));  // self-loop +1
        dl[tid] = d;
        if (tid < nn) {
            dinv[node0 + tid] = d;
            cptr[node0 + tid] = s + st64[tid];
        }
    }
    if (tid == 0 && node0 + nn == N) cptr[N] = (unsigned)E;  // sentinel
    __syncthreads();
    float* gtmp = (float*)ebuf;   // safe: all ebuf reads complete
    for (int idx2 = tid; idx2 < nn * 16; idx2 += TPB_G) {
        int n = idx2 >> 4, f = idx2 & 15;
        float vv = dl[n] * (lx[n * 3] * lw[f] + lx[n * 3 + 1] * lw[16 + f] +
                            lx[n * 3 + 2] * lw[32 + f]);
        acc1[(size_t)(node0 + n) * 16 + f] = vv;
        gtmp[idx2] = vv;
    }
    __syncthreads();
    for (int idx2 = tid; idx2 < nn * 8; idx2 += TPB_G) {
        int n = idx2 >> 3, qq = idx2 & 7;
        g1b[(size_t)(node0 + n) * 8 + qq] =
            (unsigned)f2bf(gtmp[n * 16 + 2 * qq]) |
            ((unsigned)f2bf(gtmp[n * 16 + 2 * qq + 1]) << 16);
    }
}

// ---------- consumer: 4 lanes/col, uint2 g-loads, serial register accumulate ----------
__global__ __launch_bounds__(TPB)
void k_csr(const unsigned* __restrict__ srt, const unsigned* __restrict__ cptr,
           const uint2* __restrict__ gb2, float* __restrict__ acc, int N) {
    int t = blockIdx.x * TPB + threadIdx.x;
    int c = t >> 2, f4 = t & 3;
    if (c >= N) return;
    unsigned e = cptr[c], end = cptr[c + 1];
    float s0 = 0.0f, s1 = 0.0f, s2 = 0.0f, s3 = 0.0f;
#pragma unroll 4
    for (; e < end; ++e) {
        unsigned m = srt[e];                         // same addr across 4 lanes -> merged
        float w = (float)(m >> 17) * (1.0f / 32768.0f);
        uint2 u = gb2[(size_t)(m & 0x1FFFFu) * 4 + f4];  // bf16x4, L2-resident table
        s0 = fmaf(w, __uint_as_float(u.x << 16), s0);
        s1 = fmaf(w, __uint_as_float(u.x & 0xFFFF0000u), s1);
        s2 = fmaf(w, __uint_as_float(u.y << 16), s2);
        s3 = fmaf(w, __uint_as_float(u.y & 0xFFFF0000u), s3);
    }
    float4* p = (float4*)&acc[(size_t)c * 16 + 4 * f4];
    float4 v = *p;                                   // exclusive owner: plain RMW
    v.x += s0; v.y += s1; v.z += s2; v.w += s3;
    *p = v;
}

// ---------- mid: h1 = relu(b1 + dinv*acc1); g2 = dinv*(h1@W2) -> bf16 + acc2 seed ----------
__global__ void k_mid(const float* __restrict__ acc1, const float* __restrict__ dinv,
                      const float* __restrict__ b1, const float* __restrict__ W2,
                      unsigned* __restrict__ g2b, float* __restrict__ acc2, int N) {
    __shared__ float t[16][16];
    __shared__ float go[16][16];
    __shared__ float w2[256];
    int tid = threadIdx.x;
    int il = tid >> 4, f = tid & 15;
    int i = blockIdx.x * 16 + il;
    w2[tid] = W2[tid];
    float v = 0.0f, d = 0.0f;
    if (i < N) {
        d = dinv[i];
        v = b1[f] + d * acc1[(size_t)i * 16 + f];
        v = v > 0.0f ? v : 0.0f;
    }
    t[il][f] = v;
    __syncthreads();
    float r = 0.0f;
    if (i < N) {
        float o = 0.0f;
#pragma unroll
        for (int kk = 0; kk < 16; kk++) o += t[il][kk] * w2[kk * 16 + f];
        r = d * o;
        acc2[(size_t)i * 16 + f] = r;
    }
    go[il][f] = r;
    __syncthreads();
    if (tid < 128) {
        int il2 = tid >> 3, q = tid & 7;
        int i2 = blockIdx.x * 16 + il2;
        if (i2 < N)
            g2b[(size_t)i2 * 8 + q] = (unsigned)f2bf(go[il2][2 * q]) |
                                      ((unsigned)f2bf(go[il2][2 * q + 1]) << 16);
    }
}

// ---------- pool: h2 = relu(b2 + dinv*acc2) folded into sorted-batch pool ----------
#define PC 1024
__global__ void k_pool(const float* __restrict__ acc2, const float* __restrict__ dinv,
                       const float* __restrict__ b2, const int* __restrict__ batch,
                       float* __restrict__ pooled, int N, int G) {
    int b0 = blockIdx.x * PC;
    int nodes = min(PC, N - b0);
    __shared__ float lacc[64 * 16];
    __shared__ int lbat[PC];
    int tid = threadIdx.x;  // 256
    for (int i = tid; i < nodes; i += 256) lbat[i] = batch[b0 + i];
    __syncthreads();
    int gmin = lbat[0], gmax = lbat[nodes - 1];
    bool fits = (gmax - gmin < 64);
    if (fits) {
        for (int i = tid; i < 64 * 16; i += 256) lacc[i] = 0.0f;
        __syncthreads();
    }
    for (int idx = tid; idx < nodes * 16; idx += 256) {
        int i = idx >> 4, f = idx & 15;
        int n = b0 + i;
        float d = dinv[n];
        float v = b2[f] + d * acc2[(size_t)n * 16 + f];
        v = v > 0.0f ? v : 0.0f;
        if (fits) atomicAdd(&lacc[(lbat[i] - gmin) * 16 + f], v);
        else      atomicAdd(&pooled[lbat[i] * 16 + f], v);
    }
    if (fits) {
        __syncthreads();
        for (int idx = tid; idx < 64 * 16; idx += 256) {
            int g = gmin + (idx >> 4);
            float v = lacc[idx];
            if (g < G && v != 0.0f) atomicAdd(&pooled[g * 16 + (idx & 15)], v);
        }
    }
}

__global__ void k_final(const float* __restrict__ pooled, const float* __restrict__ Wlin,
                        const float* __restrict__ blin, float* __restrict__ out, int G) {
    int t = blockIdx.x * blockDim.x + threadIdx.x;
    int g = t / 7, j = t % 7;
    if (g >= G) return;
    float v = blin[j];
#pragma unroll
    for (int f = 0; f < 16; f++) v += pooled[g * 16 + f] * Wlin[f * 7 + j];
    out[g * 7 + j] = v;
}

static inline int cdiv_i(long long a, long long b) { return (int)((a + b - 1) / b); }

extern "C" void kernel_launch(void* const* d_in, const int* in_sizes, int n_in,
                              void* d_out, int out_size, void* d_ws, size_t ws_size,
                              hipStream_t stream) {
    const float* x     = (const float*)d_in[0];
    const int*   ei    = (const int*)d_in[1];
    const float* ew    = (const float*)d_in[2];
    const int*   batch = (const int*)d_in[3];
    const float* W1    = (const float*)d_in[4];
    const float* b1    = (const float*)d_in[5];
    const float* W2    = (const float*)d_in[6];
    const float* b2    = (const float*)d_in[7];
    const float* Wlin  = (const float*)d_in[8];
    const float* blin  = (const float*)d_in[9];
    float* out = (float*)d_out;

    const int N = in_sizes[0] / 3;
    const int E = in_sizes[2];
    const int G = out_size / 7;
    const int K = (N + RB - 1) >> SH;            // fine buckets (1563)
    const int tile = cdiv_i(E, PB);
    const int* row = ei;
    const int* col = ei + E;

    // layout (8/16B alignment respected): brc | srt | dinv | g1b | g2b | acc1 | acc2
    //       | cptr | bstE | bof | [zero: bcnt | pooled]
    uint2*    brc    = (uint2*)d_ws;                        // E (8B)
    unsigned* srt    = (unsigned*)(brc + E);                // E
    float*    dinv   = (float*)(srt + E);                   // N
    unsigned* g1b    = (unsigned*)(dinv + N);               // N*8 (bf16 x16)
    unsigned* g2b    = g1b + (size_t)N * 8;                 // N*8
    float*    acc1   = (float*)(g2b + (size_t)N * 8);       // N*16
    float*    acc2   = acc1 + (size_t)N * 16;               // N*16
    unsigned* cptr   = (unsigned*)(acc2 + (size_t)N * 16);  // N+1
    unsigned* bstE   = cptr + N + 1;                        // KMAX+1
    unsigned* bof    = bstE + (KMAX + 1);                   // PB*KST
    unsigned* bcnt   = bof + (size_t)PB * KST;              // KMAX
    float*    pooled = (float*)(bcnt + KMAX);               // G*16

    hipMemsetAsync(bcnt, 0, (KMAX + (size_t)G * 16) * sizeof(unsigned), stream);

    // CSR build: fused hist+partition -> fine scan -> run-gather group
    k_part<<<PB, PT, 0, stream>>>(row, col, ew, bcnt, bof, brc, E, K, tile);
    k_scan<<<1, 1024, 0, stream>>>(bcnt, bstE, K);
    k_grp<<<K, TPB_G, 0, stream>>>(brc, bof, bstE, x, W1, srt, cptr, dinv, g1b, acc1,
                                   N, E, K);

    // layer 1: barrier-free CSR gather/reduce (4 lanes/col)
    k_csr<<<cdiv_i((long long)N * 4, TPB), TPB, 0, stream>>>(srt, cptr,
                                                             (const uint2*)g1b, acc1, N);

    // mid: h1 -> g2(bf16) + acc2 seed
    k_mid<<<cdiv_i(N, 16), TPB, 0, stream>>>(acc1, dinv, b1, W2, g2b, acc2, N);

    // layer 2
    k_csr<<<cdiv_i((long long)N * 4, TPB), TPB, 0, stream>>>(srt, cptr,
                                                             (const uint2*)g2b, acc2, N);

    // pool + head
    k_pool<<<cdiv_i(N, PC), TPB, 0, stream>>>(acc2, dinv, b2, batch, pooled, N, G);
    k_final<<<cdiv_i((long long)G * 7, TPB), TPB, 0, stream>>>(pooled, Wlin, blin, out, G);
}

// Round 10
// 270.312 us; speedup vs baseline: 1.2521x; 1.2521x over previous
//
#include <hip/hip_runtime.h>

// GCN 2-layer + pool + head, R25: R21 (best, 280us) + fused hist + temporal frontier split.
// Open-frontier model (R19-R24 post-mortem): partition write amp ~ blocks/XCD x open-line
// frontier. R21 (PB=256, 1 pass): 32 x 100KB = 3.2MB/XCD ~ L2 -> 5x amp (WRITE 113MB).
// R24 (PB=64): amp fixed but 192 CUs idle -> 130us. Fix: keep PB=256, shrink frontier
// TEMPORALLY - NP=4 bucket-range passes with barriers: open frontier ~25KB/block
// (0.8MB/XCD, L2-resident). Tile re-reads are L2-hot; scatter loop is 2% VALU so 4x loop
// overhead is free. Also fuse k_cnt's hist into k_part (block hists its tile anyway).
// k_grp (256-run seg-stamp) / k_csr (8-lane) / k_mid / k_pool / k_final = verbatim R21.
//   h[c] = b + dinv[c]*( g[c] + sum_e w_e * g[row_e] ),  g = dinv * (prev @ W)

#define SH 6
#define RB 64
#define KMAX 2048           // N <= 131072 (row packs in 17 bits)
#define KST (KMAX + 1)      // bof row stride
#define TPB 256
#define BCAP 8192           // per-bucket LDS capacity in k_grp
#define PT 1024             // k_part threads
#define PB 256              // partition grid (all CUs)
#define NP 4                // scatter passes (frontier = K/NP buckets)

typedef unsigned short ushort_t;
typedef unsigned char u8;
typedef unsigned long long u64;

__device__ __forceinline__ ushort_t f2bf(float v) {
    unsigned u = __float_as_uint(v);
    u += 0x7FFFu + ((u >> 16) & 1u);   // RNE
    return (ushort_t)(u >> 16);
}

__device__ __forceinline__ unsigned quantw(float w) {
    unsigned wq = (unsigned)__float2int_rn(w * 32768.0f);
    return wq > 32767u ? 32767u : wq;
}

// ---------- partition: fused hist(->bcnt) + local scan + NP-pass block-major scatter ----
__global__ __launch_bounds__(PT)
void k_part(const int* __restrict__ row, const int* __restrict__ col,
            const float* __restrict__ ew, unsigned* __restrict__ bcnt,
            unsigned* __restrict__ bof, uint2* __restrict__ brc,
            int E, int K, int tile, int KP) {
    __shared__ unsigned lh[KMAX];                // hist (8KB)
    __shared__ unsigned cur[KMAX];               // scatter cursors (8KB)
    __shared__ unsigned wt[PT / 64];
    int tid = threadIdx.x, b = blockIdx.x;
    int e0 = min(b * tile, E), e1 = min(b * tile + tile, E);
    unsigned base = (unsigned)e0;
    for (int i = tid; i < KMAX; i += PT) lh[i] = 0u;
    __syncthreads();
    for (int e = e0 + tid; e < e1; e += PT) atomicAdd(&lh[col[e] >> SH], 1u);
    __syncthreads();
    for (int i = tid; i < K; i += PT) {          // feed global fine counts (k_cnt fused)
        unsigned c = lh[i];
        if (c) atomicAdd(&bcnt[i], c);
    }
    // local exclusive scan of lh (2 serial/thread + wave shfl + wave totals)
    int i0 = tid << 1;
    unsigned a0 = lh[i0], a1 = lh[i0 + 1];
    unsigned ts = a0 + a1, v = ts;
#pragma unroll
    for (int o = 1; o < 64; o <<= 1) {
        unsigned u = __shfl_up(v, o, 64);
        if ((tid & 63) >= o) v += u;
    }
    if ((tid & 63) == 63) wt[tid >> 6] = v;
    __syncthreads();
    if (tid == 0) {
        unsigned acc = 0;
#pragma unroll
        for (int w = 0; w < PT / 64; w++) { unsigned t = wt[w]; wt[w] = acc; acc += t; }
    }
    __syncthreads();
    unsigned ex = wt[tid >> 6] + (v - ts);
    unsigned* bo = bof + (size_t)b * KST;
    cur[i0] = base + ex;          bo[i0] = base + ex;
    cur[i0 + 1] = base + ex + a0; bo[i0 + 1] = base + ex + a0;
    if (tid == PT - 1) bo[KMAX] = base + ex + ts;
    __syncthreads();
    // NP bucket-range passes: open write frontier ~ KP x 64B per block (L2-resident)
    for (int p = 0; p < NP; ++p) {
        int lo = p * KP, hi = min(lo + KP, K);
        for (int e = e0 + tid; e < e1; e += PT) {
            int c = col[e];
            int bkt = c >> SH;
            if (bkt >= lo && bkt < hi) {
                unsigned pos = atomicAdd(&cur[bkt], 1u);
                brc[pos] = make_uint2((unsigned)row[e] | (quantw(ew[e]) << 17),
                                      (unsigned)c);
            }
        }
        __syncthreads();                         // temporal frontier boundary
    }
}

// ---------- exclusive scan over fine counts -> bst ----------
__global__ void k_scan(const unsigned* __restrict__ cnt, unsigned* __restrict__ start,
                       int K) {
    __shared__ unsigned a[KMAX], b[KMAX];
    int t = threadIdx.x;  // 1024
    for (int i = t; i < KMAX; i += 1024) a[i] = (i < K) ? cnt[i] : 0u;
    __syncthreads();
    unsigned *src = a, *dst = b;
    for (int off = 1; off < KMAX; off <<= 1) {
        for (int i = t; i < KMAX; i += 1024)
            dst[i] = (i >= off) ? src[i] + src[i - off] : src[i];
        __syncthreads();
        unsigned* tmp = src; src = dst; dst = tmp;
    }
    for (int i = t; i < K; i += 1024) start[i] = (i == 0) ? 0u : src[i - 1];
}

// ---------- per-bucket: gather 256 runs -> group-by-col -> srt + cptr + dinv + g1/acc1 ----
__global__ __launch_bounds__(TPB)
void k_grp(const uint2* __restrict__ brc, const unsigned* __restrict__ bof,
           const unsigned* __restrict__ bst, const float* __restrict__ x,
           const float* __restrict__ W1, unsigned* __restrict__ srt,
           unsigned* __restrict__ cptr, float* __restrict__ dinv,
           unsigned* __restrict__ g1b, float* __restrict__ acc1,
           int N, int E, int K) {
    // bijective XCD-contiguous swizzle (m204): consecutive buckets share an XCD's L2
    int orig = blockIdx.x;
    int q8 = K >> 3, r8 = K & 7;
    int xcd = orig & 7, idx = orig >> 3;
    int k = (xcd < r8 ? xcd * (q8 + 1) : r8 * (q8 + 1) + (xcd - r8) * q8) + idx;
    int node0 = k << SH;

    __shared__ unsigned ebuf[BCAP];          // 32KB (reused as gtmp after scatter)
    __shared__ u8 cbuf[BCAP];                // 8KB
    __shared__ u8 seg[BCAP];                 // 8KB: j -> run id
    __shared__ unsigned rsrc[PB];            // run source starts
    __shared__ unsigned roff[PB + 1];        // exclusive prefix of run lengths
    __shared__ unsigned wt4[TPB / 64];
    __shared__ unsigned cnt64[RB], st64[RB], dq[RB];
    __shared__ float dl[RB], lx[RB * 3], lw[48];
    int tid = threadIdx.x;
    unsigned s = bst[k];
    if (tid < RB) { cnt64[tid] = 0u; dq[tid] = 0u; }
    if (tid < 48) lw[tid] = W1[tid];
    int nn = min(RB, N - node0);
    for (int i = tid; i < nn * 3; i += TPB) lx[i] = x[(size_t)node0 * 3 + i];

    // run table: rsrc/len from bof columns k, k+1; 256-entry exclusive scan
    unsigned rl;
    {
        unsigned s0 = bof[(size_t)tid * KST + k];
        unsigned s1 = bof[(size_t)tid * KST + k + 1];
        rsrc[tid] = s0;
        rl = s1 - s0;
    }
    unsigned v = rl;
#pragma unroll
    for (int o = 1; o < 64; o <<= 1) {
        unsigned u = __shfl_up(v, o, 64);
        if ((tid & 63) >= o) v += u;
    }
    if ((tid & 63) == 63) wt4[tid >> 6] = v;
    __syncthreads();
    if (tid == 0) {
        unsigned acc = 0;
#pragma unroll
        for (int w = 0; w < TPB / 64; w++) { unsigned t = wt4[w]; wt4[w] = acc; acc += t; }
    }
    __syncthreads();
    unsigned ex = wt4[tid >> 6] + (v - rl);
    roff[tid] = ex;
    if (tid == PB - 1) roff[PB] = ex + rl;
    __syncthreads();
    unsigned c = roff[PB];

    bool fits = (c <= (unsigned)BCAP);
    if (fits) {
        for (unsigned j = ex; j < ex + rl; ++j) seg[j] = (u8)tid;  // stamp run ids
        __syncthreads();
        for (unsigned j = tid; j < c; j += TPB) {
            unsigned r = seg[j];
            unsigned src = rsrc[r] + (j - roff[r]);
            uint2 p = brc[src];
            unsigned cl = p.y & 63u;
            ebuf[j] = p.x; cbuf[j] = (u8)cl;
            atomicAdd(&cnt64[cl], 1u);
            atomicAdd(&dq[cl], p.x >> 17);
        }
        __syncthreads();
        if (tid == 0) {                                  // tiny serial scan of 64
            unsigned acc = 0;
            for (int i = 0; i < RB; i++) { st64[i] = acc; acc += cnt64[i]; cnt64[i] = 0u; }
        }
        __syncthreads();
        for (unsigned j = tid; j < c; j += TPB) {
            unsigned cl = cbuf[j];
            unsigned pos = st64[cl] + atomicAdd(&cnt64[cl], 1u);
            srt[s + pos] = ebuf[j];                      // within-bucket contiguous range
        }
    } else {                                             // 2-pass fallback (rare): bsearch
#define MAP_SRC(j, srcv)                                                       \
        {                                                                      \
            int lo = 0, hi = PB - 1;                                           \
            _Pragma("unroll")                                                  \
            for (int it = 0; it < 8; ++it) {                                   \
                int mid = (lo + hi + 1) >> 1;                                  \
                if (roff[mid] <= (j)) lo = mid; else hi = mid - 1;             \
            }                                                                  \
            (srcv) = rsrc[lo] + ((j) - roff[lo]);                              \
        }
        for (unsigned j = tid; j < c; j += TPB) {
            unsigned src; MAP_SRC(j, src);
            uint2 p = brc[src];
            unsigned cl = p.y & 63u;
            atomicAdd(&cnt64[cl], 1u);
            atomicAdd(&dq[cl], p.x >> 17);
        }
        __syncthreads();
        if (tid == 0) {
            unsigned acc = 0;
            for (int i = 0; i < RB; i++) { st64[i] = acc; acc += cnt64[i]; cnt64[i] = 0u; }
        }
        __syncthreads();
        for (unsigned j = tid; j < c; j += TPB) {
            unsigned src; MAP_SRC(j, src);
            uint2 p = brc[src];
            unsigned cl = p.y & 63u;
            unsigned pos = st64[cl] + atomicAdd(&cnt64[cl], 1u);
            srt[s + pos] = p.x;
        }
#undef MAP_SRC
    }
    __syncthreads();
    if (tid < RB) {
        float d = rsqrtf(1.0f + (float)dq[tid] * (1.0f / 32768.0f));  // self-loop +1
        dl[tid] = d;
        if (tid < nn) {
            dinv[node0 + tid] = d;
            cptr[node0 + tid] = s + st64[tid];
        }
    }
    if (tid == 0 && node0 + nn == N) cptr[N] = (unsigned)E;  // sentinel
    __syncthreads();
    float* gtmp = (float*)ebuf;   // safe: all ebuf reads complete
    for (int idx2 = tid; idx2 < nn * 16; idx2 += TPB) {
        int n = idx2 >> 4, f = idx2 & 15;
        float vv = dl[n] * (lx[n * 3] * lw[f] + lx[n * 3 + 1] * lw[16 + f] +
                            lx[n * 3 + 2] * lw[32 + f]);
        acc1[(size_t)(node0 + n) * 16 + f] = vv;
        gtmp[idx2] = vv;
    }
    __syncthreads();
    for (int idx2 = tid; idx2 < nn * 8; idx2 += TPB) {
        int n = idx2 >> 3, qq = idx2 & 7;
        g1b[(size_t)(node0 + n) * 8 + qq] =
            (unsigned)f2bf(gtmp[n * 16 + 2 * qq]) |
            ((unsigned)f2bf(gtmp[n * 16 + 2 * qq + 1]) << 16);
    }
}

// ---------- consumer: 8 lanes/col, serial register accumulate, no barriers ----------
__global__ __launch_bounds__(TPB)
void k_csr(const unsigned* __restrict__ srt, const unsigned* __restrict__ cptr,
           const unsigned* __restrict__ gb, float* __restrict__ acc, int N) {
    int t = blockIdx.x * TPB + threadIdx.x;
    int c = t >> 3, f2 = t & 7;
    if (c >= N) return;
    unsigned e = cptr[c], end = cptr[c + 1];
    float a = 0.0f, b = 0.0f;
#pragma unroll 4
    for (; e < end; ++e) {
        unsigned m = srt[e];                         // same addr across 8 lanes -> merged
        float w = (float)(m >> 17) * (1.0f / 32768.0f);
        unsigned u = gb[(size_t)(m & 0x1FFFFu) * 8 + f2];  // bf16x2, L2-resident table
        a = fmaf(w, __uint_as_float(u << 16), a);
        b = fmaf(w, __uint_as_float(u & 0xFFFF0000u), b);
    }
    float2* p = (float2*)&acc[(size_t)c * 16 + 2 * f2];
    float2 v = *p;                                   // exclusive owner: plain RMW
    v.x += a; v.y += b;
    *p = v;
}

// ---------- mid: h1 = relu(b1 + dinv*acc1); g2 = dinv*(h1@W2) -> bf16 + acc2 seed ----------
__global__ void k_mid(const float* __restrict__ acc1, const float* __restrict__ dinv,
                      const float* __restrict__ b1, const float* __restrict__ W2,
                      unsigned* __restrict__ g2b, float* __restrict__ acc2, int N) {
    __shared__ float t[16][16];
    __shared__ float go[16][16];
    __shared__ float w2[256];
    int tid = threadIdx.x;
    int il = tid >> 4, f = tid & 15;
    int i = blockIdx.x * 16 + il;
    w2[tid] = W2[tid];
    float v = 0.0f, d = 0.0f;
    if (i < N) {
        d = dinv[i];
        v = b1[f] + d * acc1[(size_t)i * 16 + f];
        v = v > 0.0f ? v : 0.0f;
    }
    t[il][f] = v;
    __syncthreads();
    float r = 0.0f;
    if (i < N) {
        float o = 0.0f;
#pragma unroll
        for (int kk = 0; kk < 16; kk++) o += t[il][kk] * w2[kk * 16 + f];
        r = d * o;
        acc2[(size_t)i * 16 + f] = r;
    }
    go[il][f] = r;
    __syncthreads();
    if (tid < 128) {
        int il2 = tid >> 3, q = tid & 7;
        int i2 = blockIdx.x * 16 + il2;
        if (i2 < N)
            g2b[(size_t)i2 * 8 + q] = (unsigned)f2bf(go[il2][2 * q]) |
                                      ((unsigned)f2bf(go[il2][2 * q + 1]) << 16);
    }
}

// ---------- pool: h2 = relu(b2 + dinv*acc2) folded into sorted-batch pool ----------
#define PC 1024
__global__ void k_pool(const float* __restrict__ acc2, const float* __restrict__ dinv,
                       const float* __restrict__ b2, const int* __restrict__ batch,
                       float* __restrict__ pooled, int N, int G) {
    int b0 = blockIdx.x * PC;
    int nodes = min(PC, N - b0);
    __shared__ float lacc[64 * 16];
    __shared__ int lbat[PC];
    int tid = threadIdx.x;  // 256
    for (int i = tid; i < nodes; i += 256) lbat[i] = batch[b0 + i];
    __syncthreads();
    int gmin = lbat[0], gmax = lbat[nodes - 1];
    bool fits = (gmax - gmin < 64);
    if (fits) {
        for (int i = tid; i < 64 * 16; i += 256) lacc[i] = 0.0f;
        __syncthreads();
    }
    for (int idx = tid; idx < nodes * 16; idx += 256) {
        int i = idx >> 4, f = idx & 15;
        int n = b0 + i;
        float d = dinv[n];
        float v = b2[f] + d * acc2[(size_t)n * 16 + f];
        v = v > 0.0f ? v : 0.0f;
        if (fits) atomicAdd(&lacc[(lbat[i] - gmin) * 16 + f], v);
        else      atomicAdd(&pooled[lbat[i] * 16 + f], v);
    }
    if (fits) {
        __syncthreads();
        for (int idx = tid; idx < 64 * 16; idx += 256) {
            int g = gmin + (idx >> 4);
            float v = lacc[idx];
            if (g < G && v != 0.0f) atomicAdd(&pooled[g * 16 + (idx & 15)], v);
        }
    }
}

__global__ void k_final(const float* __restrict__ pooled, const float* __restrict__ Wlin,
                        const float* __restrict__ blin, float* __restrict__ out, int G) {
    int t = blockIdx.x * blockDim.x + threadIdx.x;
    int g = t / 7, j = t % 7;
    if (g >= G) return;
    float v = blin[j];
#pragma unroll
    for (int f = 0; f < 16; f++) v += pooled[g * 16 + f] * Wlin[f * 7 + j];
    out[g * 7 + j] = v;
}

static inline int cdiv_i(long long a, long long b) { return (int)((a + b - 1) / b); }

extern "C" void kernel_launch(void* const* d_in, const int* in_sizes, int n_in,
                              void* d_out, int out_size, void* d_ws, size_t ws_size,
                              hipStream_t stream) {
    const float* x     = (const float*)d_in[0];
    const int*   ei    = (const int*)d_in[1];
    const float* ew    = (const float*)d_in[2];
    const int*   batch = (const int*)d_in[3];
    const float* W1    = (const float*)d_in[4];
    const float* b1    = (const float*)d_in[5];
    const float* W2    = (const float*)d_in[6];
    const float* b2    = (const float*)d_in[7];
    const float* Wlin  = (const float*)d_in[8];
    const float* blin  = (const float*)d_in[9];
    float* out = (float*)d_out;

    const int N = in_sizes[0] / 3;
    const int E = in_sizes[2];
    const int G = out_size / 7;
    const int K = (N + RB - 1) >> SH;            // fine buckets (1563)
    const int tile = cdiv_i(E, PB);
    const int KP = cdiv_i(K, NP);
    const int* row = ei;
    const int* col = ei + E;

    // layout: brc(uint2) | srt | dinv | g1b | g2b | acc1 | acc2 | cptr | bst | bof
    //       | [zero: bcnt | pooled]
    uint2*    brc    = (uint2*)d_ws;                        // E (8B)
    unsigned* srt    = (unsigned*)(brc + E);                // E
    float*    dinv   = (float*)(srt + E);                   // N
    unsigned* g1b    = (unsigned*)(dinv + N);               // N*8 (bf16 x16)
    unsigned* g2b    = g1b + (size_t)N * 8;                 // N*8
    float*    acc1   = (float*)(g2b + (size_t)N * 8);       // N*16
    float*    acc2   = acc1 + (size_t)N * 16;               // N*16
    unsigned* cptr   = (unsigned*)(acc2 + (size_t)N * 16);  // N+1
    unsigned* bst    = cptr + N + 1;                        // KMAX
    unsigned* bof    = bst + KMAX;                          // PB*KST
    unsigned* bcnt   = bof + (size_t)PB * KST;              // KMAX
    float*    pooled = (float*)(bcnt + KMAX);               // G*16

    hipMemsetAsync(bcnt, 0, (KMAX + (size_t)G * 16) * sizeof(unsigned), stream);

    // CSR build: fused hist + NP-pass partition -> fine scan -> run-gather group
    k_part<<<PB, PT, 0, stream>>>(row, col, ew, bcnt, bof, brc, E, K, tile, KP);
    k_scan<<<1, 1024, 0, stream>>>(bcnt, bst, K);
    k_grp<<<K, TPB, 0, stream>>>(brc, bof, bst, x, W1, srt, cptr, dinv, g1b, acc1,
                                 N, E, K);

    // layer 1: barrier-free CSR gather/reduce
    k_csr<<<cdiv_i((long long)N * 8, TPB), TPB, 0, stream>>>(srt, cptr, g1b, acc1, N);

    // mid: h1 -> g2(bf16) + acc2 seed
    k_mid<<<cdiv_i(N, 16), TPB, 0, stream>>>(acc1, dinv, b1, W2, g2b, acc2, N);

    // layer 2
    k_csr<<<cdiv_i((long long)N * 8, TPB), TPB, 0, stream>>>(srt, cptr, g2b, acc2, N);

    // pool + head
    k_pool<<<cdiv_i(N, PC), TPB, 0, stream>>>(acc2, dinv, b2, batch, pooled, N, G);
    k_final<<<cdiv_i((long long)G * 7, TPB), TPB, 0, stream>>>(pooled, Wlin, blin, out, G);
}

// Round 11
// 252.398 us; speedup vs baseline: 1.3410x; 1.0710x over previous
//
#include <hip/hip_runtime.h>

// GCN 2-layer + pool + head, R26: R25 + LDS-staged tile in k_part (read-once partition).
// R25 (270us best): temporal frontier split fixed write amp (WRITE 113->38MB) but multi-
// pass re-reads pushed FETCH to 71-77MB (col read NP+1 times; row/ew lines touched per
// pass) at 1.9TB/s -> k_part fetch-bound at 58-62us. Fix: stage col (50KB) + payload
// row|wq15 (50KB) in LDS during the hist pass; NP bucket-range scatter passes then read
// LDS only -> every global input byte read ONCE. LDS ~116KB -> 1 blk/CU x 16 waves;
// frontier 8 blk/XCD x 25KB = 200KB L2-resident -> ~1x write amp. Fallback to global-read
// path if tile > cap. k_scan/k_grp/k_csr/k_mid/k_pool/k_final verbatim R25.
//   h[c] = b + dinv[c]*( g[c] + sum_e w_e * g[row_e] ),  g = dinv * (prev @ W)

#define SH 6
#define RB 64
#define KMAX 2048           // N <= 131072 (row packs in 17 bits)
#define KST (KMAX + 1)      // bof row stride
#define TPB 256
#define BCAP 8192           // per-bucket LDS capacity in k_grp
#define PT 1024             // k_part threads
#define PB 256              // partition grid (all CUs)
#define NP 4                // scatter passes (frontier = K/NP buckets)
#define ETCAP 12800         // k_part staged-tile capacity (2 x 50KB LDS)

typedef unsigned short ushort_t;
typedef unsigned char u8;
typedef unsigned long long u64;

__device__ __forceinline__ ushort_t f2bf(float v) {
    unsigned u = __float_as_uint(v);
    u += 0x7FFFu + ((u >> 16) & 1u);   // RNE
    return (ushort_t)(u >> 16);
}

__device__ __forceinline__ unsigned quantw(float w) {
    unsigned wq = (unsigned)__float2int_rn(w * 32768.0f);
    return wq > 32767u ? 32767u : wq;
}

// ---------- partition: staged tile + fused hist(->bcnt) + NP-pass scatter ----------
__global__ __launch_bounds__(PT)
void k_part(const int* __restrict__ row, const int* __restrict__ col,
            const float* __restrict__ ew, unsigned* __restrict__ bcnt,
            unsigned* __restrict__ bof, uint2* __restrict__ brc,
            int E, int K, int tile, int KP) {
    __shared__ unsigned lh[KMAX];                // hist (8KB)
    __shared__ unsigned cur[KMAX];               // scatter cursors (8KB)
    __shared__ unsigned wt[PT / 64];
    __shared__ unsigned lc[ETCAP];               // staged col (50KB)
    __shared__ unsigned lp[ETCAP];               // staged payload row|wq15 (50KB)
    int tid = threadIdx.x, b = blockIdx.x;
    int e0 = min(b * tile, E), e1 = min(b * tile + tile, E);
    int cnt = e1 - e0;
    unsigned base = (unsigned)e0;
    bool staged = (cnt <= ETCAP);
    for (int i = tid; i < KMAX; i += PT) lh[i] = 0u;
    __syncthreads();
    if (staged) {
        for (int j = tid; j < cnt; j += PT) {    // single read of col/row/ew
            int e = e0 + j;
            int c = col[e];
            lc[j] = (unsigned)c;
            lp[j] = (unsigned)row[e] | (quantw(ew[e]) << 17);
            atomicAdd(&lh[c >> SH], 1u);
        }
    } else {
        for (int e = e0 + tid; e < e1; e += PT) atomicAdd(&lh[col[e] >> SH], 1u);
    }
    __syncthreads();
    for (int i = tid; i < K; i += PT) {          // feed global fine counts (k_cnt fused)
        unsigned c = lh[i];
        if (c) atomicAdd(&bcnt[i], c);
    }
    // local exclusive scan of lh (2 serial/thread + wave shfl + wave totals)
    int i0 = tid << 1;
    unsigned a0 = lh[i0], a1 = lh[i0 + 1];
    unsigned ts = a0 + a1, v = ts;
#pragma unroll
    for (int o = 1; o < 64; o <<= 1) {
        unsigned u = __shfl_up(v, o, 64);
        if ((tid & 63) >= o) v += u;
    }
    if ((tid & 63) == 63) wt[tid >> 6] = v;
    __syncthreads();
    if (tid == 0) {
        unsigned acc = 0;
#pragma unroll
        for (int w = 0; w < PT / 64; w++) { unsigned t = wt[w]; wt[w] = acc; acc += t; }
    }
    __syncthreads();
    unsigned ex = wt[tid >> 6] + (v - ts);
    unsigned* bo = bof + (size_t)b * KST;
    cur[i0] = base + ex;          bo[i0] = base + ex;
    cur[i0 + 1] = base + ex + a0; bo[i0 + 1] = base + ex + a0;
    if (tid == PT - 1) bo[KMAX] = base + ex + ts;
    __syncthreads();
    // NP bucket-range passes: open write frontier ~ KP x 64B per block (L2-resident)
    for (int p = 0; p < NP; ++p) {
        int lo = p * KP, hi = min(lo + KP, K);
        if (staged) {
            for (int j = tid; j < cnt; j += PT) {
                unsigned c = lc[j];
                int bkt = (int)(c >> SH);
                if (bkt >= lo && bkt < hi) {
                    unsigned pos = atomicAdd(&cur[bkt], 1u);
                    brc[pos] = make_uint2(lp[j], c);
                }
            }
        } else {
            for (int e = e0 + tid; e < e1; e += PT) {
                int c = col[e];
                int bkt = c >> SH;
                if (bkt >= lo && bkt < hi) {
                    unsigned pos = atomicAdd(&cur[bkt], 1u);
                    brc[pos] = make_uint2((unsigned)row[e] | (quantw(ew[e]) << 17),
                                          (unsigned)c);
                }
            }
        }
        __syncthreads();                         // temporal frontier boundary
    }
}

// ---------- exclusive scan over fine counts -> bst ----------
__global__ void k_scan(const unsigned* __restrict__ cnt, unsigned* __restrict__ start,
                       int K) {
    __shared__ unsigned a[KMAX], b[KMAX];
    int t = threadIdx.x;  // 1024
    for (int i = t; i < KMAX; i += 1024) a[i] = (i < K) ? cnt[i] : 0u;
    __syncthreads();
    unsigned *src = a, *dst = b;
    for (int off = 1; off < KMAX; off <<= 1) {
        for (int i = t; i < KMAX; i += 1024)
            dst[i] = (i >= off) ? src[i] + src[i - off] : src[i];
        __syncthreads();
        unsigned* tmp = src; src = dst; dst = tmp;
    }
    for (int i = t; i < K; i += 1024) start[i] = (i == 0) ? 0u : src[i - 1];
}

// ---------- per-bucket: gather 256 runs -> group-by-col -> srt + cptr + dinv + g1/acc1 ----
__global__ __launch_bounds__(TPB)
void k_grp(const uint2* __restrict__ brc, const unsigned* __restrict__ bof,
           const unsigned* __restrict__ bst, const float* __restrict__ x,
           const float* __restrict__ W1, unsigned* __restrict__ srt,
           unsigned* __restrict__ cptr, float* __restrict__ dinv,
           unsigned* __restrict__ g1b, float* __restrict__ acc1,
           int N, int E, int K) {
    // bijective XCD-contiguous swizzle (m204): consecutive buckets share an XCD's L2
    int orig = blockIdx.x;
    int q8 = K >> 3, r8 = K & 7;
    int xcd = orig & 7, idx = orig >> 3;
    int k = (xcd < r8 ? xcd * (q8 + 1) : r8 * (q8 + 1) + (xcd - r8) * q8) + idx;
    int node0 = k << SH;

    __shared__ unsigned ebuf[BCAP];          // 32KB (reused as gtmp after scatter)
    __shared__ u8 cbuf[BCAP];                // 8KB
    __shared__ u8 seg[BCAP];                 // 8KB: j -> run id
    __shared__ unsigned rsrc[PB];            // run source starts
    __shared__ unsigned roff[PB + 1];        // exclusive prefix of run lengths
    __shared__ unsigned wt4[TPB / 64];
    __shared__ unsigned cnt64[RB], st64[RB], dq[RB];
    __shared__ float dl[RB], lx[RB * 3], lw[48];
    int tid = threadIdx.x;
    unsigned s = bst[k];
    if (tid < RB) { cnt64[tid] = 0u; dq[tid] = 0u; }
    if (tid < 48) lw[tid] = W1[tid];
    int nn = min(RB, N - node0);
    for (int i = tid; i < nn * 3; i += TPB) lx[i] = x[(size_t)node0 * 3 + i];

    // run table: rsrc/len from bof columns k, k+1; 256-entry exclusive scan
    unsigned rl;
    {
        unsigned s0 = bof[(size_t)tid * KST + k];
        unsigned s1 = bof[(size_t)tid * KST + k + 1];
        rsrc[tid] = s0;
        rl = s1 - s0;
    }
    unsigned v = rl;
#pragma unroll
    for (int o = 1; o < 64; o <<= 1) {
        unsigned u = __shfl_up(v, o, 64);
        if ((tid & 63) >= o) v += u;
    }
    if ((tid & 63) == 63) wt4[tid >> 6] = v;
    __syncthreads();
    if (tid == 0) {
        unsigned acc = 0;
#pragma unroll
        for (int w = 0; w < TPB / 64; w++) { unsigned t = wt4[w]; wt4[w] = acc; acc += t; }
    }
    __syncthreads();
    unsigned ex = wt4[tid >> 6] + (v - rl);
    roff[tid] = ex;
    if (tid == PB - 1) roff[PB] = ex + rl;
    __syncthreads();
    unsigned c = roff[PB];

    bool fits = (c <= (unsigned)BCAP);
    if (fits) {
        for (unsigned j = ex; j < ex + rl; ++j) seg[j] = (u8)tid;  // stamp run ids
        __syncthreads();
        for (unsigned j = tid; j < c; j += TPB) {
            unsigned r = seg[j];
            unsigned src = rsrc[r] + (j - roff[r]);
            uint2 p = brc[src];
            unsigned cl = p.y & 63u;
            ebuf[j] = p.x; cbuf[j] = (u8)cl;
            atomicAdd(&cnt64[cl], 1u);
            atomicAdd(&dq[cl], p.x >> 17);
        }
        __syncthreads();
        if (tid == 0) {                                  // tiny serial scan of 64
            unsigned acc = 0;
            for (int i = 0; i < RB; i++) { st64[i] = acc; acc += cnt64[i]; cnt64[i] = 0u; }
        }
        __syncthreads();
        for (unsigned j = tid; j < c; j += TPB) {
            unsigned cl = cbuf[j];
            unsigned pos = st64[cl] + atomicAdd(&cnt64[cl], 1u);
            srt[s + pos] = ebuf[j];                      // within-bucket contiguous range
        }
    } else {                                             // 2-pass fallback (rare): bsearch
#define MAP_SRC(j, srcv)                                                       \
        {                                                                      \
            int lo = 0, hi = PB - 1;                                           \
            _Pragma("unroll")                                                  \
            for (int it = 0; it < 8; ++it) {                                   \
                int mid = (lo + hi + 1) >> 1;                                  \
                if (roff[mid] <= (j)) lo = mid; else hi = mid - 1;             \
            }                                                                  \
            (srcv) = rsrc[lo] + ((j) - roff[lo]);                              \
        }
        for (unsigned j = tid; j < c; j += TPB) {
            unsigned src; MAP_SRC(j, src);
            uint2 p = brc[src];
            unsigned cl = p.y & 63u;
            atomicAdd(&cnt64[cl], 1u);
            atomicAdd(&dq[cl], p.x >> 17);
        }
        __syncthreads();
        if (tid == 0) {
            unsigned acc = 0;
            for (int i = 0; i < RB; i++) { st64[i] = acc; acc += cnt64[i]; cnt64[i] = 0u; }
        }
        __syncthreads();
        for (unsigned j = tid; j < c; j += TPB) {
            unsigned src; MAP_SRC(j, src);
            uint2 p = brc[src];
            unsigned cl = p.y & 63u;
            unsigned pos = st64[cl] + atomicAdd(&cnt64[cl], 1u);
            srt[s + pos] = p.x;
        }
#undef MAP_SRC
    }
    __syncthreads();
    if (tid < RB) {
        float d = rsqrtf(1.0f + (float)dq[tid] * (1.0f / 32768.0f));  // self-loop +1
        dl[tid] = d;
        if (tid < nn) {
            dinv[node0 + tid] = d;
            cptr[node0 + tid] = s + st64[tid];
        }
    }
    if (tid == 0 && node0 + nn == N) cptr[N] = (unsigned)E;  // sentinel
    __syncthreads();
    float* gtmp = (float*)ebuf;   // safe: all ebuf reads complete
    for (int idx2 = tid; idx2 < nn * 16; idx2 += TPB) {
        int n = idx2 >> 4, f = idx2 & 15;
        float vv = dl[n] * (lx[n * 3] * lw[f] + lx[n * 3 + 1] * lw[16 + f] +
                            lx[n * 3 + 2] * lw[32 + f]);
        acc1[(size_t)(node0 + n) * 16 + f] = vv;
        gtmp[idx2] = vv;
    }
    __syncthreads();
    for (int idx2 = tid; idx2 < nn * 8; idx2 += TPB) {
        int n = idx2 >> 3, qq = idx2 & 7;
        g1b[(size_t)(node0 + n) * 8 + qq] =
            (unsigned)f2bf(gtmp[n * 16 + 2 * qq]) |
            ((unsigned)f2bf(gtmp[n * 16 + 2 * qq + 1]) << 16);
    }
}

// ---------- consumer: 8 lanes/col, serial register accumulate, no barriers ----------
__global__ __launch_bounds__(TPB)
void k_csr(const unsigned* __restrict__ srt, const unsigned* __restrict__ cptr,
           const unsigned* __restrict__ gb, float* __restrict__ acc, int N) {
    int t = blockIdx.x * TPB + threadIdx.x;
    int c = t >> 3, f2 = t & 7;
    if (c >= N) return;
    unsigned e = cptr[c], end = cptr[c + 1];
    float a = 0.0f, b = 0.0f;
#pragma unroll 4
    for (; e < end; ++e) {
        unsigned m = srt[e];                         // same addr across 8 lanes -> merged
        float w = (float)(m >> 17) * (1.0f / 32768.0f);
        unsigned u = gb[(size_t)(m & 0x1FFFFu) * 8 + f2];  // bf16x2, L2-resident table
        a = fmaf(w, __uint_as_float(u << 16), a);
        b = fmaf(w, __uint_as_float(u & 0xFFFF0000u), b);
    }
    float2* p = (float2*)&acc[(size_t)c * 16 + 2 * f2];
    float2 v = *p;                                   // exclusive owner: plain RMW
    v.x += a; v.y += b;
    *p = v;
}

// ---------- mid: h1 = relu(b1 + dinv*acc1); g2 = dinv*(h1@W2) -> bf16 + acc2 seed ----------
__global__ void k_mid(const float* __restrict__ acc1, const float* __restrict__ dinv,
                      const float* __restrict__ b1, const float* __restrict__ W2,
                      unsigned* __restrict__ g2b, float* __restrict__ acc2, int N) {
    __shared__ float t[16][16];
    __shared__ float go[16][16];
    __shared__ float w2[256];
    int tid = threadIdx.x;
    int il = tid >> 4, f = tid & 15;
    int i = blockIdx.x * 16 + il;
    w2[tid] = W2[tid];
    float v = 0.0f, d = 0.0f;
    if (i < N) {
        d = dinv[i];
        v = b1[f] + d * acc1[(size_t)i * 16 + f];
        v = v > 0.0f ? v : 0.0f;
    }
    t[il][f] = v;
    __syncthreads();
    float r = 0.0f;
    if (i < N) {
        float o = 0.0f;
#pragma unroll
        for (int kk = 0; kk < 16; kk++) o += t[il][kk] * w2[kk * 16 + f];
        r = d * o;
        acc2[(size_t)i * 16 + f] = r;
    }
    go[il][f] = r;
    __syncthreads();
    if (tid < 128) {
        int il2 = tid >> 3, q = tid & 7;
        int i2 = blockIdx.x * 16 + il2;
        if (i2 < N)
            g2b[(size_t)i2 * 8 + q] = (unsigned)f2bf(go[il2][2 * q]) |
                                      ((unsigned)f2bf(go[il2][2 * q + 1]) << 16);
    }
}

// ---------- pool: h2 = relu(b2 + dinv*acc2) folded into sorted-batch pool ----------
#define PC 1024
__global__ void k_pool(const float* __restrict__ acc2, const float* __restrict__ dinv,
                       const float* __restrict__ b2, const int* __restrict__ batch,
                       float* __restrict__ pooled, int N, int G) {
    int b0 = blockIdx.x * PC;
    int nodes = min(PC, N - b0);
    __shared__ float lacc[64 * 16];
    __shared__ int lbat[PC];
    int tid = threadIdx.x;  // 256
    for (int i = tid; i < nodes; i += 256) lbat[i] = batch[b0 + i];
    __syncthreads();
    int gmin = lbat[0], gmax = lbat[nodes - 1];
    bool fits = (gmax - gmin < 64);
    if (fits) {
        for (int i = tid; i < 64 * 16; i += 256) lacc[i] = 0.0f;
        __syncthreads();
    }
    for (int idx = tid; idx < nodes * 16; idx += 256) {
        int i = idx >> 4, f = idx & 15;
        int n = b0 + i;
        float d = dinv[n];
        float v = b2[f] + d * acc2[(size_t)n * 16 + f];
        v = v > 0.0f ? v : 0.0f;
        if (fits) atomicAdd(&lacc[(lbat[i] - gmin) * 16 + f], v);
        else      atomicAdd(&pooled[lbat[i] * 16 + f], v);
    }
    if (fits) {
        __syncthreads();
        for (int idx = tid; idx < 64 * 16; idx += 256) {
            int g = gmin + (idx >> 4);
            float v = lacc[idx];
            if (g < G && v != 0.0f) atomicAdd(&pooled[g * 16 + (idx & 15)], v);
        }
    }
}

__global__ void k_final(const float* __restrict__ pooled, const float* __restrict__ Wlin,
                        const float* __restrict__ blin, float* __restrict__ out, int G) {
    int t = blockIdx.x * blockDim.x + threadIdx.x;
    int g = t / 7, j = t % 7;
    if (g >= G) return;
    float v = blin[j];
#pragma unroll
    for (int f = 0; f < 16; f++) v += pooled[g * 16 + f] * Wlin[f * 7 + j];
    out[g * 7 + j] = v;
}

static inline int cdiv_i(long long a, long long b) { return (int)((a + b - 1) / b); }

extern "C" void kernel_launch(void* const* d_in, const int* in_sizes, int n_in,
                              void* d_out, int out_size, void* d_ws, size_t ws_size,
                              hipStream_t stream) {
    const float* x     = (const float*)d_in[0];
    const int*   ei    = (const int*)d_in[1];
    const float* ew    = (const float*)d_in[2];
    const int*   batch = (const int*)d_in[3];
    const float* W1    = (const float*)d_in[4];
    const float* b1    = (const float*)d_in[5];
    const float* W2    = (const float*)d_in[6];
    const float* b2    = (const float*)d_in[7];
    const float* Wlin  = (const float*)d_in[8];
    const float* blin  = (const float*)d_in[9];
    float* out = (float*)d_out;

    const int N = in_sizes[0] / 3;
    const int E = in_sizes[2];
    const int G = out_size / 7;
    const int K = (N + RB - 1) >> SH;            // fine buckets (1563)
    const int tile = cdiv_i(E, PB);
    const int KP = cdiv_i(K, NP);
    const int* row = ei;
    const int* col = ei + E;

    // layout: brc(uint2) | srt | dinv | g1b | g2b | acc1 | acc2 | cptr | bst | bof
    //       | [zero: bcnt | pooled]
    uint2*    brc    = (uint2*)d_ws;                        // E (8B)
    unsigned* srt    = (unsigned*)(brc + E);                // E
    float*    dinv   = (float*)(srt + E);                   // N
    unsigned* g1b    = (unsigned*)(dinv + N);               // N*8 (bf16 x16)
    unsigned* g2b    = g1b + (size_t)N * 8;                 // N*8
    float*    acc1   = (float*)(g2b + (size_t)N * 8);       // N*16
    float*    acc2   = acc1 + (size_t)N * 16;               // N*16
    unsigned* cptr   = (unsigned*)(acc2 + (size_t)N * 16);  // N+1
    unsigned* bst    = cptr + N + 1;                        // KMAX
    unsigned* bof    = bst + KMAX;                          // PB*KST
    unsigned* bcnt   = bof + (size_t)PB * KST;              // KMAX
    float*    pooled = (float*)(bcnt + KMAX);               // G*16

    hipMemsetAsync(bcnt, 0, (KMAX + (size_t)G * 16) * sizeof(unsigned), stream);

    // CSR build: staged-tile partition (read-once) -> fine scan -> run-gather group
    k_part<<<PB, PT, 0, stream>>>(row, col, ew, bcnt, bof, brc, E, K, tile, KP);
    k_scan<<<1, 1024, 0, stream>>>(bcnt, bst, K);
    k_grp<<<K, TPB, 0, stream>>>(brc, bof, bst, x, W1, srt, cptr, dinv, g1b, acc1,
                                 N, E, K);

    // layer 1: barrier-free CSR gather/reduce
    k_csr<<<cdiv_i((long long)N * 8, TPB), TPB, 0, stream>>>(srt, cptr, g1b, acc1, N);

    // mid: h1 -> g2(bf16) + acc2 seed
    k_mid<<<cdiv_i(N, 16), TPB, 0, stream>>>(acc1, dinv, b1, W2, g2b, acc2, N);

    // layer 2
    k_csr<<<cdiv_i((long long)N * 8, TPB), TPB, 0, stream>>>(srt, cptr, g2b, acc2, N);

    // pool + head
    k_pool<<<cdiv_i(N, PC), TPB, 0, stream>>>(acc2, dinv, b2, batch, pooled, N, G);
    k_final<<<cdiv_i((long long)G * 7, TPB), TPB, 0, stream>>>(pooled, Wlin, blin, out, G);
}

// Round 12
// 250.476 us; speedup vs baseline: 1.3513x; 1.0077x over previous
//
#include <hip/hip_runtime.h>

// GCN 2-layer + pool + head, R27: R26 + 4-lane consumers + k_mid fused into layer-1.
// R26 (252us best): top dispatch is now the HARNESS's 256MiB workspace poison (42us at
// HBM roofline - fixed overhead). Our kernels: k_part ~30, k_grp ~45, k_csr x2 ~55,
// k_mid ~8. This round attacks the consumer pair:
//   k_csr1: 4 lanes/col (uint2 g-loads, half the waves of 8-lane) + k_mid FUSED -
//           after the edge loop the 4 owner lanes hold the full acc1 row; compute
//           h1=relu(b1+d*acc1) in-register, __shfl-assemble 16 h across the group,
//           W2 matmul in k_mid's kk order, write acc2 seed + g2b directly.
//           Deletes k_mid launch + 12.8MB acc1 round-trip.
//   k_csr2: plain 4-lane RMW consumer for layer 2.
// Producer side (k_part staged-tile read-once, k_scan, k_grp) verbatim R26.
//   h[c] = b + dinv[c]*( g[c] + sum_e w_e * g[row_e] ),  g = dinv * (prev @ W)

#define SH 6
#define RB 64
#define KMAX 2048           // N <= 131072 (row packs in 17 bits)
#define KST (KMAX + 1)      // bof row stride
#define TPB 256
#define BCAP 8192           // per-bucket LDS capacity in k_grp
#define PT 1024             // k_part threads
#define PB 256              // partition grid (all CUs)
#define NP 4                // scatter passes (frontier = K/NP buckets)
#define ETCAP 12800         // k_part staged-tile capacity (2 x 50KB LDS)

typedef unsigned short ushort_t;
typedef unsigned char u8;
typedef unsigned long long u64;

__device__ __forceinline__ ushort_t f2bf(float v) {
    unsigned u = __float_as_uint(v);
    u += 0x7FFFu + ((u >> 16) & 1u);   // RNE
    return (ushort_t)(u >> 16);
}

__device__ __forceinline__ unsigned quantw(float w) {
    unsigned wq = (unsigned)__float2int_rn(w * 32768.0f);
    return wq > 32767u ? 32767u : wq;
}

// ---------- partition: staged tile + fused hist(->bcnt) + NP-pass scatter ----------
__global__ __launch_bounds__(PT)
void k_part(const int* __restrict__ row, const int* __restrict__ col,
            const float* __restrict__ ew, unsigned* __restrict__ bcnt,
            unsigned* __restrict__ bof, uint2* __restrict__ brc,
            int E, int K, int tile, int KP) {
    __shared__ unsigned lh[KMAX];                // hist (8KB)
    __shared__ unsigned cur[KMAX];               // scatter cursors (8KB)
    __shared__ unsigned wt[PT / 64];
    __shared__ unsigned lc[ETCAP];               // staged col (50KB)
    __shared__ unsigned lp[ETCAP];               // staged payload row|wq15 (50KB)
    int tid = threadIdx.x, b = blockIdx.x;
    int e0 = min(b * tile, E), e1 = min(b * tile + tile, E);
    int cnt = e1 - e0;
    unsigned base = (unsigned)e0;
    bool staged = (cnt <= ETCAP);
    for (int i = tid; i < KMAX; i += PT) lh[i] = 0u;
    __syncthreads();
    if (staged) {
        for (int j = tid; j < cnt; j += PT) {    // single read of col/row/ew
            int e = e0 + j;
            int c = col[e];
            lc[j] = (unsigned)c;
            lp[j] = (unsigned)row[e] | (quantw(ew[e]) << 17);
            atomicAdd(&lh[c >> SH], 1u);
        }
    } else {
        for (int e = e0 + tid; e < e1; e += PT) atomicAdd(&lh[col[e] >> SH], 1u);
    }
    __syncthreads();
    for (int i = tid; i < K; i += PT) {          // feed global fine counts (k_cnt fused)
        unsigned c = lh[i];
        if (c) atomicAdd(&bcnt[i], c);
    }
    // local exclusive scan of lh (2 serial/thread + wave shfl + wave totals)
    int i0 = tid << 1;
    unsigned a0 = lh[i0], a1 = lh[i0 + 1];
    unsigned ts = a0 + a1, v = ts;
#pragma unroll
    for (int o = 1; o < 64; o <<= 1) {
        unsigned u = __shfl_up(v, o, 64);
        if ((tid & 63) >= o) v += u;
    }
    if ((tid & 63) == 63) wt[tid >> 6] = v;
    __syncthreads();
    if (tid == 0) {
        unsigned acc = 0;
#pragma unroll
        for (int w = 0; w < PT / 64; w++) { unsigned t = wt[w]; wt[w] = acc; acc += t; }
    }
    __syncthreads();
    unsigned ex = wt[tid >> 6] + (v - ts);
    unsigned* bo = bof + (size_t)b * KST;
    cur[i0] = base + ex;          bo[i0] = base + ex;
    cur[i0 + 1] = base + ex + a0; bo[i0 + 1] = base + ex + a0;
    if (tid == PT - 1) bo[KMAX] = base + ex + ts;
    __syncthreads();
    // NP bucket-range passes: open write frontier ~ KP x 64B per block (L2-resident)
    for (int p = 0; p < NP; ++p) {
        int lo = p * KP, hi = min(lo + KP, K);
        if (staged) {
            for (int j = tid; j < cnt; j += PT) {
                unsigned c = lc[j];
                int bkt = (int)(c >> SH);
                if (bkt >= lo && bkt < hi) {
                    unsigned pos = atomicAdd(&cur[bkt], 1u);
                    brc[pos] = make_uint2(lp[j], c);
                }
            }
        } else {
            for (int e = e0 + tid; e < e1; e += PT) {
                int c = col[e];
                int bkt = c >> SH;
                if (bkt >= lo && bkt < hi) {
                    unsigned pos = atomicAdd(&cur[bkt], 1u);
                    brc[pos] = make_uint2((unsigned)row[e] | (quantw(ew[e]) << 17),
                                          (unsigned)c);
                }
            }
        }
        __syncthreads();                         // temporal frontier boundary
    }
}

// ---------- exclusive scan over fine counts -> bst ----------
__global__ void k_scan(const unsigned* __restrict__ cnt, unsigned* __restrict__ start,
                       int K) {
    __shared__ unsigned a[KMAX], b[KMAX];
    int t = threadIdx.x;  // 1024
    for (int i = t; i < KMAX; i += 1024) a[i] = (i < K) ? cnt[i] : 0u;
    __syncthreads();
    unsigned *src = a, *dst = b;
    for (int off = 1; off < KMAX; off <<= 1) {
        for (int i = t; i < KMAX; i += 1024)
            dst[i] = (i >= off) ? src[i] + src[i - off] : src[i];
        __syncthreads();
        unsigned* tmp = src; src = dst; dst = tmp;
    }
    for (int i = t; i < K; i += 1024) start[i] = (i == 0) ? 0u : src[i - 1];
}

// ---------- per-bucket: gather 256 runs -> group-by-col -> srt + cptr + dinv + g1/acc1 ----
__global__ __launch_bounds__(TPB)
void k_grp(const uint2* __restrict__ brc, const unsigned* __restrict__ bof,
           const unsigned* __restrict__ bst, const float* __restrict__ x,
           const float* __restrict__ W1, unsigned* __restrict__ srt,
           unsigned* __restrict__ cptr, float* __restrict__ dinv,
           unsigned* __restrict__ g1b, float* __restrict__ acc1,
           int N, int E, int K) {
    // bijective XCD-contiguous swizzle (m204): consecutive buckets share an XCD's L2
    int orig = blockIdx.x;
    int q8 = K >> 3, r8 = K & 7;
    int xcd = orig & 7, idx = orig >> 3;
    int k = (xcd < r8 ? xcd * (q8 + 1) : r8 * (q8 + 1) + (xcd - r8) * q8) + idx;
    int node0 = k << SH;

    __shared__ unsigned ebuf[BCAP];          // 32KB (reused as gtmp after scatter)
    __shared__ u8 cbuf[BCAP];                // 8KB
    __shared__ u8 seg[BCAP];                 // 8KB: j -> run id
    __shared__ unsigned rsrc[PB];            // run source starts
    __shared__ unsigned roff[PB + 1];        // exclusive prefix of run lengths
    __shared__ unsigned wt4[TPB / 64];
    __shared__ unsigned cnt64[RB], st64[RB], dq[RB];
    __shared__ float dl[RB], lx[RB * 3], lw[48];
    int tid = threadIdx.x;
    unsigned s = bst[k];
    if (tid < RB) { cnt64[tid] = 0u; dq[tid] = 0u; }
    if (tid < 48) lw[tid] = W1[tid];
    int nn = min(RB, N - node0);
    for (int i = tid; i < nn * 3; i += TPB) lx[i] = x[(size_t)node0 * 3 + i];

    // run table: rsrc/len from bof columns k, k+1; 256-entry exclusive scan
    unsigned rl;
    {
        unsigned s0 = bof[(size_t)tid * KST + k];
        unsigned s1 = bof[(size_t)tid * KST + k + 1];
        rsrc[tid] = s0;
        rl = s1 - s0;
    }
    unsigned v = rl;
#pragma unroll
    for (int o = 1; o < 64; o <<= 1) {
        unsigned u = __shfl_up(v, o, 64);
        if ((tid & 63) >= o) v += u;
    }
    if ((tid & 63) == 63) wt4[tid >> 6] = v;
    __syncthreads();
    if (tid == 0) {
        unsigned acc = 0;
#pragma unroll
        for (int w = 0; w < TPB / 64; w++) { unsigned t = wt4[w]; wt4[w] = acc; acc += t; }
    }
    __syncthreads();
    unsigned ex = wt4[tid >> 6] + (v - rl);
    roff[tid] = ex;
    if (tid == PB - 1) roff[PB] = ex + rl;
    __syncthreads();
    unsigned c = roff[PB];

    bool fits = (c <= (unsigned)BCAP);
    if (fits) {
        for (unsigned j = ex; j < ex + rl; ++j) seg[j] = (u8)tid;  // stamp run ids
        __syncthreads();
        for (unsigned j = tid; j < c; j += TPB) {
            unsigned r = seg[j];
            unsigned src = rsrc[r] + (j - roff[r]);
            uint2 p = brc[src];
            unsigned cl = p.y & 63u;
            ebuf[j] = p.x; cbuf[j] = (u8)cl;
            atomicAdd(&cnt64[cl], 1u);
            atomicAdd(&dq[cl], p.x >> 17);
        }
        __syncthreads();
        if (tid == 0) {                                  // tiny serial scan of 64
            unsigned acc = 0;
            for (int i = 0; i < RB; i++) { st64[i] = acc; acc += cnt64[i]; cnt64[i] = 0u; }
        }
        __syncthreads();
        for (unsigned j = tid; j < c; j += TPB) {
            unsigned cl = cbuf[j];
            unsigned pos = st64[cl] + atomicAdd(&cnt64[cl], 1u);
            srt[s + pos] = ebuf[j];                      // within-bucket contiguous range
        }
    } else {                                             // 2-pass fallback (rare): bsearch
#define MAP_SRC(j, srcv)                                                       \
        {                                                                      \
            int lo = 0, hi = PB - 1;                                           \
            _Pragma("unroll")                                                  \
            for (int it = 0; it < 8; ++it) {                                   \
                int mid = (lo + hi + 1) >> 1;                                  \
                if (roff[mid] <= (j)) lo = mid; else hi = mid - 1;             \
            }                                                                  \
            (srcv) = rsrc[lo] + ((j) - roff[lo]);                              \
        }
        for (unsigned j = tid; j < c; j += TPB) {
            unsigned src; MAP_SRC(j, src);
            uint2 p = brc[src];
            unsigned cl = p.y & 63u;
            atomicAdd(&cnt64[cl], 1u);
            atomicAdd(&dq[cl], p.x >> 17);
        }
        __syncthreads();
        if (tid == 0) {
            unsigned acc = 0;
            for (int i = 0; i < RB; i++) { st64[i] = acc; acc += cnt64[i]; cnt64[i] = 0u; }
        }
        __syncthreads();
        for (unsigned j = tid; j < c; j += TPB) {
            unsigned src; MAP_SRC(j, src);
            uint2 p = brc[src];
            unsigned cl = p.y & 63u;
            unsigned pos = st64[cl] + atomicAdd(&cnt64[cl], 1u);
            srt[s + pos] = p.x;
        }
#undef MAP_SRC
    }
    __syncthreads();
    if (tid < RB) {
        float d = rsqrtf(1.0f + (float)dq[tid] * (1.0f / 32768.0f));  // self-loop +1
        dl[tid] = d;
        if (tid < nn) {
            dinv[node0 + tid] = d;
            cptr[node0 + tid] = s + st64[tid];
        }
    }
    if (tid == 0 && node0 + nn == N) cptr[N] = (unsigned)E;  // sentinel
    __syncthreads();
    float* gtmp = (float*)ebuf;   // safe: all ebuf reads complete
    for (int idx2 = tid; idx2 < nn * 16; idx2 += TPB) {
        int n = idx2 >> 4, f = idx2 & 15;
        float vv = dl[n] * (lx[n * 3] * lw[f] + lx[n * 3 + 1] * lw[16 + f] +
                            lx[n * 3 + 2] * lw[32 + f]);
        acc1[(size_t)(node0 + n) * 16 + f] = vv;
        gtmp[idx2] = vv;
    }
    __syncthreads();
    for (int idx2 = tid; idx2 < nn * 8; idx2 += TPB) {
        int n = idx2 >> 3, qq = idx2 & 7;
        g1b[(size_t)(node0 + n) * 8 + qq] =
            (unsigned)f2bf(gtmp[n * 16 + 2 * qq]) |
            ((unsigned)f2bf(gtmp[n * 16 + 2 * qq + 1]) << 16);
    }
}

// ---------- layer-1 consumer + mid fused: 4 lanes/col, in-register W2 matmul ----------
__global__ __launch_bounds__(TPB)
void k_csr1(const unsigned* __restrict__ srt, const unsigned* __restrict__ cptr,
            const uint2* __restrict__ gb2, const float* __restrict__ acc1,
            const float* __restrict__ dinv, const float* __restrict__ b1,
            const float* __restrict__ W2, unsigned* __restrict__ g2b,
            float* __restrict__ acc2, int N) {
    int t = blockIdx.x * TPB + threadIdx.x;
    int c = t >> 2, f4 = t & 3;
    if (c >= N) return;
    unsigned e = cptr[c], end = cptr[c + 1];
    float s0 = 0.0f, s1 = 0.0f, s2 = 0.0f, s3 = 0.0f;
#pragma unroll 4
    for (; e < end; ++e) {
        unsigned m = srt[e];                         // same addr across 4 lanes -> merged
        float w = (float)(m >> 17) * (1.0f / 32768.0f);
        uint2 u = gb2[(size_t)(m & 0x1FFFFu) * 4 + f4];  // bf16x4, L2-resident table
        s0 = fmaf(w, __uint_as_float(u.x << 16), s0);
        s1 = fmaf(w, __uint_as_float(u.x & 0xFFFF0000u), s1);
        s2 = fmaf(w, __uint_as_float(u.y << 16), s2);
        s3 = fmaf(w, __uint_as_float(u.y & 0xFFFF0000u), s3);
    }
    float d = dinv[c];
    const float4 se = *(const float4*)&acc1[(size_t)c * 16 + 4 * f4];  // g[c] self seed
    const float4 bb = *(const float4*)&b1[4 * f4];
    float h[4];
    h[0] = fmaxf(bb.x + d * (se.x + s0), 0.0f);      // == relu(b1 + d*acc1_final)
    h[1] = fmaxf(bb.y + d * (se.y + s1), 0.0f);
    h[2] = fmaxf(bb.z + d * (se.z + s2), 0.0f);
    h[3] = fmaxf(bb.w + d * (se.w + s3), 0.0f);
    // o[f] = sum_kk h_all[kk] * W2[kk][f]  (kk ascending, same order as k_mid)
    int base = (threadIdx.x & 63) & ~3;              // group's first lane in wave
    float o0 = 0.0f, o1 = 0.0f, o2 = 0.0f, o3 = 0.0f;
#pragma unroll
    for (int kk = 0; kk < 16; ++kk) {
        float hk = __shfl(h[kk & 3], base + (kk >> 2), 64);
        const float4 wv = *(const float4*)&W2[kk * 16 + 4 * f4];
        o0 = fmaf(hk, wv.x, o0);
        o1 = fmaf(hk, wv.y, o1);
        o2 = fmaf(hk, wv.z, o2);
        o3 = fmaf(hk, wv.w, o3);
    }
    float r0 = d * o0, r1 = d * o1, r2 = d * o2, r3 = d * o3;
    *(float4*)&acc2[(size_t)c * 16 + 4 * f4] = make_float4(r0, r1, r2, r3);
    g2b[(size_t)c * 8 + 2 * f4]     = (unsigned)f2bf(r0) | ((unsigned)f2bf(r1) << 16);
    g2b[(size_t)c * 8 + 2 * f4 + 1] = (unsigned)f2bf(r2) | ((unsigned)f2bf(r3) << 16);
}

// ---------- layer-2 consumer: 4 lanes/col, plain RMW ----------
__global__ __launch_bounds__(TPB)
void k_csr2(const unsigned* __restrict__ srt, const unsigned* __restrict__ cptr,
            const uint2* __restrict__ gb2, float* __restrict__ acc, int N) {
    int t = blockIdx.x * TPB + threadIdx.x;
    int c = t >> 2, f4 = t & 3;
    if (c >= N) return;
    unsigned e = cptr[c], end = cptr[c + 1];
    float s0 = 0.0f, s1 = 0.0f, s2 = 0.0f, s3 = 0.0f;
#pragma unroll 4
    for (; e < end; ++e) {
        unsigned m = srt[e];
        float w = (float)(m >> 17) * (1.0f / 32768.0f);
        uint2 u = gb2[(size_t)(m & 0x1FFFFu) * 4 + f4];
        s0 = fmaf(w, __uint_as_float(u.x << 16), s0);
        s1 = fmaf(w, __uint_as_float(u.x & 0xFFFF0000u), s1);
        s2 = fmaf(w, __uint_as_float(u.y << 16), s2);
        s3 = fmaf(w, __uint_as_float(u.y & 0xFFFF0000u), s3);
    }
    float4* p = (float4*)&acc[(size_t)c * 16 + 4 * f4];
    float4 v = *p;                                   // exclusive owner: plain RMW
    v.x += s0; v.y += s1; v.z += s2; v.w += s3;
    *p = v;
}

// ---------- pool: h2 = relu(b2 + dinv*acc2) folded into sorted-batch pool ----------
#define PC 1024
__global__ void k_pool(const float* __restrict__ acc2, const float* __restrict__ dinv,
                       const float* __restrict__ b2, const int* __restrict__ batch,
                       float* __restrict__ pooled, int N, int G) {
    int b0 = blockIdx.x * PC;
    int nodes = min(PC, N - b0);
    __shared__ float lacc[64 * 16];
    __shared__ int lbat[PC];
    int tid = threadIdx.x;  // 256
    for (int i = tid; i < nodes; i += 256) lbat[i] = batch[b0 + i];
    __syncthreads();
    int gmin = lbat[0], gmax = lbat[nodes - 1];
    bool fits = (gmax - gmin < 64);
    if (fits) {
        for (int i = tid; i < 64 * 16; i += 256) lacc[i] = 0.0f;
        __syncthreads();
    }
    for (int idx = tid; idx < nodes * 16; idx += 256) {
        int i = idx >> 4, f = idx & 15;
        int n = b0 + i;
        float d = dinv[n];
        float v = b2[f] + d * acc2[(size_t)n * 16 + f];
        v = v > 0.0f ? v : 0.0f;
        if (fits) atomicAdd(&lacc[(lbat[i] - gmin) * 16 + f], v);
        else      atomicAdd(&pooled[lbat[i] * 16 + f], v);
    }
    if (fits) {
        __syncthreads();
        for (int idx = tid; idx < 64 * 16; idx += 256) {
            int g = gmin + (idx >> 4);
            float v = lacc[idx];
            if (g < G && v != 0.0f) atomicAdd(&pooled[g * 16 + (idx & 15)], v);
        }
    }
}

__global__ void k_final(const float* __restrict__ pooled, const float* __restrict__ Wlin,
                        const float* __restrict__ blin, float* __restrict__ out, int G) {
    int t = blockIdx.x * blockDim.x + threadIdx.x;
    int g = t / 7, j = t % 7;
    if (g >= G) return;
    float v = blin[j];
#pragma unroll
    for (int f = 0; f < 16; f++) v += pooled[g * 16 + f] * Wlin[f * 7 + j];
    out[g * 7 + j] = v;
}

static inline int cdiv_i(long long a, long long b) { return (int)((a + b - 1) / b); }

extern "C" void kernel_launch(void* const* d_in, const int* in_sizes, int n_in,
                              void* d_out, int out_size, void* d_ws, size_t ws_size,
                              hipStream_t stream) {
    const float* x     = (const float*)d_in[0];
    const int*   ei    = (const int*)d_in[1];
    const float* ew    = (const float*)d_in[2];
    const int*   batch = (const int*)d_in[3];
    const float* W1    = (const float*)d_in[4];
    const float* b1    = (const float*)d_in[5];
    const float* W2    = (const float*)d_in[6];
    const float* b2    = (const float*)d_in[7];
    const float* Wlin  = (const float*)d_in[8];
    const float* blin  = (const float*)d_in[9];
    float* out = (float*)d_out;

    const int N = in_sizes[0] / 3;
    const int E = in_sizes[2];
    const int G = out_size / 7;
    const int K = (N + RB - 1) >> SH;            // fine buckets (1563)
    const int tile = cdiv_i(E, PB);
    const int KP = cdiv_i(K, NP);
    const int* row = ei;
    const int* col = ei + E;

    // layout: brc(uint2) | srt | dinv | g1b | g2b | acc1 | acc2 | cptr | bst | bof
    //       | [zero: bcnt | pooled]
    uint2*    brc    = (uint2*)d_ws;                        // E (8B)
    unsigned* srt    = (unsigned*)(brc + E);                // E
    float*    dinv   = (float*)(srt + E);                   // N
    unsigned* g1b    = (unsigned*)(dinv + N);               // N*8 (bf16 x16)
    unsigned* g2b    = g1b + (size_t)N * 8;                 // N*8
    float*    acc1   = (float*)(g2b + (size_t)N * 8);       // N*16
    float*    acc2   = acc1 + (size_t)N * 16;               // N*16
    unsigned* cptr   = (unsigned*)(acc2 + (size_t)N * 16);  // N+1
    unsigned* bst    = cptr + N + 1;                        // KMAX
    unsigned* bof    = bst + KMAX;                          // PB*KST
    unsigned* bcnt   = bof + (size_t)PB * KST;              // KMAX
    float*    pooled = (float*)(bcnt + KMAX);               // G*16

    hipMemsetAsync(bcnt, 0, (KMAX + (size_t)G * 16) * sizeof(unsigned), stream);

    // CSR build: staged-tile partition (read-once) -> fine scan -> run-gather group
    k_part<<<PB, PT, 0, stream>>>(row, col, ew, bcnt, bof, brc, E, K, tile, KP);
    k_scan<<<1, 1024, 0, stream>>>(bcnt, bst, K);
    k_grp<<<K, TPB, 0, stream>>>(brc, bof, bst, x, W1, srt, cptr, dinv, g1b, acc1,
                                 N, E, K);

    // layer 1 + mid fused: 4-lane consumer -> g2b + acc2 seed
    k_csr1<<<cdiv_i((long long)N * 4, TPB), TPB, 0, stream>>>(
        srt, cptr, (const uint2*)g1b, acc1, dinv, b1, W2, g2b, acc2, N);

    // layer 2: 4-lane consumer
    k_csr2<<<cdiv_i((long long)N * 4, TPB), TPB, 0, stream>>>(
        srt, cptr, (const uint2*)g2b, acc2, N);

    // pool + head
    k_pool<<<cdiv_i(N, PC), TPB, 0, stream>>>(acc2, dinv, b2, batch, pooled, N, G);
    k_final<<<cdiv_i((long long)G * 7, TPB), TPB, 0, stream>>>(pooled, Wlin, blin, out, G);
}

// Round 13
// 221.443 us; speedup vs baseline: 1.5284x; 1.1311x over previous
//
#include <hip/hip_runtime.h>

// GCN 2-layer + pool + head, R28: launch-count + occupancy round on R27 (250us).
// Top-5 dispatches are the harness's 256MiB poison (~43us, fixed). Our kernels ~142us +
// ~60us of launch gaps. Changes:
//   (1) k_grp BCAP 8192->4096: LDS 52->28KB, 3->5 blocks/CU (avg bucket 2047, sigma 45;
//       oversize hits existing bsearch fallback).
//   (2) k_scan fused into k_part: last-block ticket (post-syncthreads device atomic) runs
//       the 2048-entry scan -> bst with coherent atomicAdd(p,0) reads. -1 launch.
//   (3) k_pool fused into k_csr2: owner lanes hold final acc2 row; h2=relu(b2+d*acc2)
//       in-register, sorted-batch LDS pool (64 cols/block span <= a few graphs).
//       Deletes acc2 write-back + pool re-read. -1 launch.
//   h[c] = b + dinv[c]*( g[c] + sum_e w_e * g[row_e] ),  g = dinv * (prev @ W)

#define SH 6
#define RB 64
#define KMAX 2048           // N <= 131072 (row packs in 17 bits)
#define KST (KMAX + 1)      // bof row stride
#define TPB 256
#define BCAP 4096           // per-bucket LDS capacity in k_grp (avg bucket ~2047)
#define PT 1024             // k_part threads
#define PB 256              // partition grid (all CUs)
#define NP 4                // scatter passes (frontier = K/NP buckets)
#define ETCAP 12800         // k_part staged-tile capacity (2 x 50KB LDS)
#define GSPAN 16            // k_csr2 pooled LDS graph span

typedef unsigned short ushort_t;
typedef unsigned char u8;
typedef unsigned long long u64;

__device__ __forceinline__ ushort_t f2bf(float v) {
    unsigned u = __float_as_uint(v);
    u += 0x7FFFu + ((u >> 16) & 1u);   // RNE
    return (ushort_t)(u >> 16);
}

__device__ __forceinline__ unsigned quantw(float w) {
    unsigned wq = (unsigned)__float2int_rn(w * 32768.0f);
    return wq > 32767u ? 32767u : wq;
}

// ---------- partition: staged tile + fused hist(->bcnt) + fused scan + NP-pass scatter ----
__global__ __launch_bounds__(PT)
void k_part(const int* __restrict__ row, const int* __restrict__ col,
            const float* __restrict__ ew, unsigned* __restrict__ bcnt,
            unsigned* __restrict__ done, unsigned* __restrict__ bst,
            unsigned* __restrict__ bof, uint2* __restrict__ brc,
            int E, int K, int tile, int KP) {
    __shared__ unsigned lh[KMAX];                // hist (8KB)
    __shared__ unsigned cur[KMAX];               // scatter cursors (8KB)
    __shared__ unsigned wt[PT / 64];
    __shared__ unsigned lastFlag;
    __shared__ unsigned lc[ETCAP];               // staged col (50KB)
    __shared__ unsigned lp[ETCAP];               // staged payload row|wq15 (50KB)
    int tid = threadIdx.x, b = blockIdx.x;
    int e0 = min(b * tile, E), e1 = min(b * tile + tile, E);
    int cnt = e1 - e0;
    unsigned base = (unsigned)e0;
    bool staged = (cnt <= ETCAP);
    for (int i = tid; i < KMAX; i += PT) lh[i] = 0u;
    __syncthreads();
    if (staged) {
        for (int j = tid; j < cnt; j += PT) {    // single read of col/row/ew
            int e = e0 + j;
            int c = col[e];
            lc[j] = (unsigned)c;
            lp[j] = (unsigned)row[e] | (quantw(ew[e]) << 17);
            atomicAdd(&lh[c >> SH], 1u);
        }
    } else {
        for (int e = e0 + tid; e < e1; e += PT) atomicAdd(&lh[col[e] >> SH], 1u);
    }
    __syncthreads();
    for (int i = tid; i < K; i += PT) {          // feed global fine counts
        unsigned c = lh[i];
        if (c) atomicAdd(&bcnt[i], c);
    }
    __syncthreads();                             // all this block's feeds complete
    if (tid == 0) {
        __threadfence();
        lastFlag = (atomicAdd(done, 1u) == (unsigned)(gridDim.x - 1)) ? 1u : 0u;
    }
    __syncthreads();
    if (lastFlag) {                              // last block: global scan bcnt -> bst
        int i0g = tid << 1;
        unsigned g0 = (i0g < K) ? atomicAdd(&bcnt[i0g], 0u) : 0u;       // coherent read
        unsigned g1 = (i0g + 1 < K) ? atomicAdd(&bcnt[i0g + 1], 0u) : 0u;
        unsigned ts = g0 + g1, v = ts;
#pragma unroll
        for (int o = 1; o < 64; o <<= 1) {
            unsigned u = __shfl_up(v, o, 64);
            if ((tid & 63) >= o) v += u;
        }
        if ((tid & 63) == 63) wt[tid >> 6] = v;
        __syncthreads();
        if (tid == 0) {
            unsigned acc = 0;
#pragma unroll
            for (int w = 0; w < PT / 64; w++) { unsigned t = wt[w]; wt[w] = acc; acc += t; }
        }
        __syncthreads();
        unsigned ex = wt[tid >> 6] + (v - ts);
        if (i0g < K) bst[i0g] = ex;
        if (i0g + 1 < K) bst[i0g + 1] = ex + g0;
        __syncthreads();                         // wt free for local scan
    }
    // local exclusive scan of lh (2 serial/thread + wave shfl + wave totals)
    int i0 = tid << 1;
    unsigned a0 = lh[i0], a1 = lh[i0 + 1];
    unsigned ts = a0 + a1, v = ts;
#pragma unroll
    for (int o = 1; o < 64; o <<= 1) {
        unsigned u = __shfl_up(v, o, 64);
        if ((tid & 63) >= o) v += u;
    }
    if ((tid & 63) == 63) wt[tid >> 6] = v;
    __syncthreads();
    if (tid == 0) {
        unsigned acc = 0;
#pragma unroll
        for (int w = 0; w < PT / 64; w++) { unsigned t = wt[w]; wt[w] = acc; acc += t; }
    }
    __syncthreads();
    unsigned ex = wt[tid >> 6] + (v - ts);
    unsigned* bo = bof + (size_t)b * KST;
    cur[i0] = base + ex;          bo[i0] = base + ex;
    cur[i0 + 1] = base + ex + a0; bo[i0 + 1] = base + ex + a0;
    if (tid == PT - 1) bo[KMAX] = base + ex + ts;
    __syncthreads();
    // NP bucket-range passes: open write frontier ~ KP x 64B per block (L2-resident)
    for (int p = 0; p < NP; ++p) {
        int lo = p * KP, hi = min(lo + KP, K);
        if (staged) {
            for (int j = tid; j < cnt; j += PT) {
                unsigned c = lc[j];
                int bkt = (int)(c >> SH);
                if (bkt >= lo && bkt < hi) {
                    unsigned pos = atomicAdd(&cur[bkt], 1u);
                    brc[pos] = make_uint2(lp[j], c);
                }
            }
        } else {
            for (int e = e0 + tid; e < e1; e += PT) {
                int c = col[e];
                int bkt = c >> SH;
                if (bkt >= lo && bkt < hi) {
                    unsigned pos = atomicAdd(&cur[bkt], 1u);
                    brc[pos] = make_uint2((unsigned)row[e] | (quantw(ew[e]) << 17),
                                          (unsigned)c);
                }
            }
        }
        __syncthreads();                         // temporal frontier boundary
    }
}

// ---------- per-bucket: gather 256 runs -> group-by-col -> srt + cptr + dinv + g1/acc1 ----
__global__ __launch_bounds__(TPB)
void k_grp(const uint2* __restrict__ brc, const unsigned* __restrict__ bof,
           const unsigned* __restrict__ bst, const float* __restrict__ x,
           const float* __restrict__ W1, unsigned* __restrict__ srt,
           unsigned* __restrict__ cptr, float* __restrict__ dinv,
           unsigned* __restrict__ g1b, float* __restrict__ acc1,
           int N, int E, int K) {
    // bijective XCD-contiguous swizzle (m204): consecutive buckets share an XCD's L2
    int orig = blockIdx.x;
    int q8 = K >> 3, r8 = K & 7;
    int xcd = orig & 7, idx = orig >> 3;
    int k = (xcd < r8 ? xcd * (q8 + 1) : r8 * (q8 + 1) + (xcd - r8) * q8) + idx;
    int node0 = k << SH;

    __shared__ unsigned ebuf[BCAP];          // 16KB (reused as gtmp after scatter)
    __shared__ u8 cbuf[BCAP];                // 4KB
    __shared__ u8 seg[BCAP];                 // 4KB: j -> run id
    __shared__ unsigned rsrc[PB];            // run source starts
    __shared__ unsigned roff[PB + 1];        // exclusive prefix of run lengths
    __shared__ unsigned wt4[TPB / 64];
    __shared__ unsigned cnt64[RB], st64[RB], dq[RB];
    __shared__ float dl[RB], lx[RB * 3], lw[48];
    int tid = threadIdx.x;
    unsigned s = bst[k];
    if (tid < RB) { cnt64[tid] = 0u; dq[tid] = 0u; }
    if (tid < 48) lw[tid] = W1[tid];
    int nn = min(RB, N - node0);
    for (int i = tid; i < nn * 3; i += TPB) lx[i] = x[(size_t)node0 * 3 + i];

    // run table: rsrc/len from bof columns k, k+1; 256-entry exclusive scan
    unsigned rl;
    {
        unsigned s0 = bof[(size_t)tid * KST + k];
        unsigned s1 = bof[(size_t)tid * KST + k + 1];
        rsrc[tid] = s0;
        rl = s1 - s0;
    }
    unsigned v = rl;
#pragma unroll
    for (int o = 1; o < 64; o <<= 1) {
        unsigned u = __shfl_up(v, o, 64);
        if ((tid & 63) >= o) v += u;
    }
    if ((tid & 63) == 63) wt4[tid >> 6] = v;
    __syncthreads();
    if (tid == 0) {
        unsigned acc = 0;
#pragma unroll
        for (int w = 0; w < TPB / 64; w++) { unsigned t = wt4[w]; wt4[w] = acc; acc += t; }
    }
    __syncthreads();
    unsigned ex = wt4[tid >> 6] + (v - rl);
    roff[tid] = ex;
    if (tid == PB - 1) roff[PB] = ex + rl;
    __syncthreads();
    unsigned c = roff[PB];

    bool fits = (c <= (unsigned)BCAP);
    if (fits) {
        for (unsigned j = ex; j < ex + rl; ++j) seg[j] = (u8)tid;  // stamp run ids
        __syncthreads();
        for (unsigned j = tid; j < c; j += TPB) {
            unsigned r = seg[j];
            unsigned src = rsrc[r] + (j - roff[r]);
            uint2 p = brc[src];
            unsigned cl = p.y & 63u;
            ebuf[j] = p.x; cbuf[j] = (u8)cl;
            atomicAdd(&cnt64[cl], 1u);
            atomicAdd(&dq[cl], p.x >> 17);
        }
        __syncthreads();
        if (tid == 0) {                                  // tiny serial scan of 64
            unsigned acc = 0;
            for (int i = 0; i < RB; i++) { st64[i] = acc; acc += cnt64[i]; cnt64[i] = 0u; }
        }
        __syncthreads();
        for (unsigned j = tid; j < c; j += TPB) {
            unsigned cl = cbuf[j];
            unsigned pos = st64[cl] + atomicAdd(&cnt64[cl], 1u);
            srt[s + pos] = ebuf[j];                      // within-bucket contiguous range
        }
    } else {                                             // 2-pass fallback (rare): bsearch
#define MAP_SRC(j, srcv)                                                       \
        {                                                                      \
            int lo = 0, hi = PB - 1;                                           \
            _Pragma("unroll")                                                  \
            for (int it = 0; it < 8; ++it) {                                   \
                int mid = (lo + hi + 1) >> 1;                                  \
                if (roff[mid] <= (j)) lo = mid; else hi = mid - 1;             \
            }                                                                  \
            (srcv) = rsrc[lo] + ((j) - roff[lo]);                              \
        }
        for (unsigned j = tid; j < c; j += TPB) {
            unsigned src; MAP_SRC(j, src);
            uint2 p = brc[src];
            unsigned cl = p.y & 63u;
            atomicAdd(&cnt64[cl], 1u);
            atomicAdd(&dq[cl], p.x >> 17);
        }
        __syncthreads();
        if (tid == 0) {
            unsigned acc = 0;
            for (int i = 0; i < RB; i++) { st64[i] = acc; acc += cnt64[i]; cnt64[i] = 0u; }
        }
        __syncthreads();
        for (unsigned j = tid; j < c; j += TPB) {
            unsigned src; MAP_SRC(j, src);
            uint2 p = brc[src];
            unsigned cl = p.y & 63u;
            unsigned pos = st64[cl] + atomicAdd(&cnt64[cl], 1u);
            srt[s + pos] = p.x;
        }
#undef MAP_SRC
    }
    __syncthreads();
    if (tid < RB) {
        float d = rsqrtf(1.0f + (float)dq[tid] * (1.0f / 32768.0f));  // self-loop +1
        dl[tid] = d;
        if (tid < nn) {
            dinv[node0 + tid] = d;
            cptr[node0 + tid] = s + st64[tid];
        }
    }
    if (tid == 0 && node0 + nn == N) cptr[N] = (unsigned)E;  // sentinel
    __syncthreads();
    float* gtmp = (float*)ebuf;   // safe: all ebuf reads complete (nn*16 <= BCAP)
    for (int idx2 = tid; idx2 < nn * 16; idx2 += TPB) {
        int n = idx2 >> 4, f = idx2 & 15;
        float vv = dl[n] * (lx[n * 3] * lw[f] + lx[n * 3 + 1] * lw[16 + f] +
                            lx[n * 3 + 2] * lw[32 + f]);
        acc1[(size_t)(node0 + n) * 16 + f] = vv;
        gtmp[idx2] = vv;
    }
    __syncthreads();
    for (int idx2 = tid; idx2 < nn * 8; idx2 += TPB) {
        int n = idx2 >> 3, qq = idx2 & 7;
        g1b[(size_t)(node0 + n) * 8 + qq] =
            (unsigned)f2bf(gtmp[n * 16 + 2 * qq]) |
            ((unsigned)f2bf(gtmp[n * 16 + 2 * qq + 1]) << 16);
    }
}

// ---------- layer-1 consumer + mid fused: 4 lanes/col, in-register W2 matmul ----------
__global__ __launch_bounds__(TPB)
void k_csr1(const unsigned* __restrict__ srt, const unsigned* __restrict__ cptr,
            const uint2* __restrict__ gb2, const float* __restrict__ acc1,
            const float* __restrict__ dinv, const float* __restrict__ b1,
            const float* __restrict__ W2, unsigned* __restrict__ g2b,
            float* __restrict__ acc2, int N) {
    int t = blockIdx.x * TPB + threadIdx.x;
    int c = t >> 2, f4 = t & 3;
    if (c >= N) return;
    unsigned e = cptr[c], end = cptr[c + 1];
    float s0 = 0.0f, s1 = 0.0f, s2 = 0.0f, s3 = 0.0f;
#pragma unroll 4
    for (; e < end; ++e) {
        unsigned m = srt[e];                         // same addr across 4 lanes -> merged
        float w = (float)(m >> 17) * (1.0f / 32768.0f);
        uint2 u = gb2[(size_t)(m & 0x1FFFFu) * 4 + f4];  // bf16x4, L2-resident table
        s0 = fmaf(w, __uint_as_float(u.x << 16), s0);
        s1 = fmaf(w, __uint_as_float(u.x & 0xFFFF0000u), s1);
        s2 = fmaf(w, __uint_as_float(u.y << 16), s2);
        s3 = fmaf(w, __uint_as_float(u.y & 0xFFFF0000u), s3);
    }
    float d = dinv[c];
    const float4 se = *(const float4*)&acc1[(size_t)c * 16 + 4 * f4];  // g[c] self seed
    const float4 bb = *(const float4*)&b1[4 * f4];
    float h[4];
    h[0] = fmaxf(bb.x + d * (se.x + s0), 0.0f);      // == relu(b1 + d*acc1_final)
    h[1] = fmaxf(bb.y + d * (se.y + s1), 0.0f);
    h[2] = fmaxf(bb.z + d * (se.z + s2), 0.0f);
    h[3] = fmaxf(bb.w + d * (se.w + s3), 0.0f);
    // o[f] = sum_kk h_all[kk] * W2[kk][f]  (kk ascending, same order as old k_mid)
    int base = (threadIdx.x & 63) & ~3;              // group's first lane in wave
    float o0 = 0.0f, o1 = 0.0f, o2 = 0.0f, o3 = 0.0f;
#pragma unroll
    for (int kk = 0; kk < 16; ++kk) {
        float hk = __shfl(h[kk & 3], base + (kk >> 2), 64);
        const float4 wv = *(const float4*)&W2[kk * 16 + 4 * f4];
        o0 = fmaf(hk, wv.x, o0);
        o1 = fmaf(hk, wv.y, o1);
        o2 = fmaf(hk, wv.z, o2);
        o3 = fmaf(hk, wv.w, o3);
    }
    float r0 = d * o0, r1 = d * o1, r2 = d * o2, r3 = d * o3;
    *(float4*)&acc2[(size_t)c * 16 + 4 * f4] = make_float4(r0, r1, r2, r3);
    g2b[(size_t)c * 8 + 2 * f4]     = (unsigned)f2bf(r0) | ((unsigned)f2bf(r1) << 16);
    g2b[(size_t)c * 8 + 2 * f4 + 1] = (unsigned)f2bf(r2) | ((unsigned)f2bf(r3) << 16);
}

// ---------- layer-2 consumer + pool fused: 4 lanes/col, sorted-batch LDS pool ----------
__global__ __launch_bounds__(TPB)
void k_csr2(const unsigned* __restrict__ srt, const unsigned* __restrict__ cptr,
            const uint2* __restrict__ gb2, const float* __restrict__ acc2,
            const float* __restrict__ dinv, const float* __restrict__ b2,
            const int* __restrict__ batch, float* __restrict__ pooled,
            int N, int G) {
    __shared__ float lacc[GSPAN * 16];               // 1KB graph accum
    __shared__ int lb[64];
    int tid = threadIdx.x;
    int t = blockIdx.x * TPB + tid;
    int c = t >> 2, f4 = t & 3;
    int c0 = blockIdx.x * 64;
    int ncols = min(64, N - c0);
    if (tid < ncols) lb[tid] = batch[c0 + tid];
    if (tid < GSPAN * 16) lacc[tid] = 0.0f;
    __syncthreads();
    int gmin = lb[0], gmax = lb[ncols - 1];
    bool fits = (gmax - gmin) < GSPAN;

    float h0 = 0.0f, h1 = 0.0f, h2 = 0.0f, h3 = 0.0f;
    if (c < N) {
        unsigned e = cptr[c], end = cptr[c + 1];
        float s0 = 0.0f, s1 = 0.0f, s2 = 0.0f, s3 = 0.0f;
#pragma unroll 4
        for (; e < end; ++e) {
            unsigned m = srt[e];
            float w = (float)(m >> 17) * (1.0f / 32768.0f);
            uint2 u = gb2[(size_t)(m & 0x1FFFFu) * 4 + f4];
            s0 = fmaf(w, __uint_as_float(u.x << 16), s0);
            s1 = fmaf(w, __uint_as_float(u.x & 0xFFFF0000u), s1);
            s2 = fmaf(w, __uint_as_float(u.y << 16), s2);
            s3 = fmaf(w, __uint_as_float(u.y & 0xFFFF0000u), s3);
        }
        float d = dinv[c];
        const float4 se = *(const float4*)&acc2[(size_t)c * 16 + 4 * f4];  // self seed
        const float4 bb = *(const float4*)&b2[4 * f4];
        h0 = fmaxf(bb.x + d * (se.x + s0), 0.0f);    // h2 = relu(b2 + d*acc2_final)
        h1 = fmaxf(bb.y + d * (se.y + s1), 0.0f);
        h2 = fmaxf(bb.z + d * (se.z + s2), 0.0f);
        h3 = fmaxf(bb.w + d * (se.w + s3), 0.0f);
        int g = lb[c - c0];
        if (fits) {
            int o = (g - gmin) * 16 + 4 * f4;
            atomicAdd(&lacc[o],     h0);
            atomicAdd(&lacc[o + 1], h1);
            atomicAdd(&lacc[o + 2], h2);
            atomicAdd(&lacc[o + 3], h3);
        } else {
            atomicAdd(&pooled[(size_t)g * 16 + 4 * f4],     h0);
            atomicAdd(&pooled[(size_t)g * 16 + 4 * f4 + 1], h1);
            atomicAdd(&pooled[(size_t)g * 16 + 4 * f4 + 2], h2);
            atomicAdd(&pooled[(size_t)g * 16 + 4 * f4 + 3], h3);
        }
    }
    if (fits) {
        __syncthreads();
        if (tid < GSPAN * 16) {
            int g = gmin + (tid >> 4);
            float v = lacc[tid];
            if (g < G && v != 0.0f) atomicAdd(&pooled[(size_t)g * 16 + (tid & 15)], v);
        }
    }
}

__global__ void k_final(const float* __restrict__ pooled, const float* __restrict__ Wlin,
                        const float* __restrict__ blin, float* __restrict__ out, int G) {
    int t = blockIdx.x * blockDim.x + threadIdx.x;
    int g = t / 7, j = t % 7;
    if (g >= G) return;
    float v = blin[j];
#pragma unroll
    for (int f = 0; f < 16; f++) v += pooled[g * 16 + f] * Wlin[f * 7 + j];
    out[g * 7 + j] = v;
}

static inline int cdiv_i(long long a, long long b) { return (int)((a + b - 1) / b); }

extern "C" void kernel_launch(void* const* d_in, const int* in_sizes, int n_in,
                              void* d_out, int out_size, void* d_ws, size_t ws_size,
                              hipStream_t stream) {
    const float* x     = (const float*)d_in[0];
    const int*   ei    = (const int*)d_in[1];
    const float* ew    = (const float*)d_in[2];
    const int*   batch = (const int*)d_in[3];
    const float* W1    = (const float*)d_in[4];
    const float* b1    = (const float*)d_in[5];
    const float* W2    = (const float*)d_in[6];
    const float* b2    = (const float*)d_in[7];
    const float* Wlin  = (const float*)d_in[8];
    const float* blin  = (const float*)d_in[9];
    float* out = (float*)d_out;

    const int N = in_sizes[0] / 3;
    const int E = in_sizes[2];
    const int G = out_size / 7;
    const int K = (N + RB - 1) >> SH;            // fine buckets (1563)
    const int tile = cdiv_i(E, PB);
    const int KP = cdiv_i(K, NP);
    const int* row = ei;
    const int* col = ei + E;

    // layout: brc(uint2) | srt | dinv | g1b | g2b | acc1 | acc2 | cptr | bst | bof
    //       | [zero: bcnt | done | pooled]
    uint2*    brc    = (uint2*)d_ws;                        // E (8B)
    unsigned* srt    = (unsigned*)(brc + E);                // E
    float*    dinv   = (float*)(srt + E);                   // N
    unsigned* g1b    = (unsigned*)(dinv + N);               // N*8 (bf16 x16)
    unsigned* g2b    = g1b + (size_t)N * 8;                 // N*8
    float*    acc1   = (float*)(g2b + (size_t)N * 8);       // N*16
    float*    acc2   = acc1 + (size_t)N * 16;               // N*16
    unsigned* cptr   = (unsigned*)(acc2 + (size_t)N * 16);  // N+1
    unsigned* bst    = cptr + N + 1;                        // KMAX
    unsigned* bof    = bst + KMAX;                          // PB*KST
    unsigned* bcnt   = bof + (size_t)PB * KST;              // KMAX
    unsigned* done   = bcnt + KMAX;                         // 1
    float*    pooled = (float*)(done + 1);                  // G*16

    hipMemsetAsync(bcnt, 0, (KMAX + 1 + (size_t)G * 16) * sizeof(unsigned), stream);

    // CSR build: staged-tile partition (read-once, fused hist + fused scan) -> group
    k_part<<<PB, PT, 0, stream>>>(row, col, ew, bcnt, done, bst, bof, brc,
                                  E, K, tile, KP);
    k_grp<<<K, TPB, 0, stream>>>(brc, bof, bst, x, W1, srt, cptr, dinv, g1b, acc1,
                                 N, E, K);

    // layer 1 + mid fused: 4-lane consumer -> g2b + acc2 seed
    k_csr1<<<cdiv_i((long long)N * 4, TPB), TPB, 0, stream>>>(
        srt, cptr, (const uint2*)g1b, acc1, dinv, b1, W2, g2b, acc2, N);

    // layer 2 + pool fused: 4-lane consumer -> pooled
    k_csr2<<<cdiv_i((long long)N * 4, TPB), TPB, 0, stream>>>(
        srt, cptr, (const uint2*)g2b, acc2, dinv, b2, batch, pooled, N, G);

    // head
    k_final<<<cdiv_i((long long)G * 7, TPB), TPB, 0, stream>>>(pooled, Wlin, blin, out, G);
}